// Round 12
// baseline (60.521 us; speedup 1.0000x reference)
//
#include <hip/hip_runtime.h>
#include <math.h>
#include <utility>

#define NB 16
#define NS 2048
#define NE 8
#define NH 2
#define NF 512
#define DEG 6
#define NMONO 210          // #monomials in 4 vars, total degree <= 6
#define KPB 64             // keys per k1 block
#define NCHUNK 32          // key chunks per (b,h)
#define PHI_LD 66          // fp16 row stride (64 keys + 2 pad)
#define QPB 128
#define LNEPS 1e-5f
#define PART_STRIDE (5 * NMONO)

typedef float f32x2 __attribute__((ext_vector_type(2)));
typedef _Float16 h2 __attribute__((ext_vector_type(2)));

#if defined(__has_builtin)
# if __has_builtin(__builtin_amdgcn_fdot2)
#  define FDOT2(a,b,c) __builtin_amdgcn_fdot2((a),(b),(c),false)
# endif
#endif
#ifndef FDOT2
static __device__ __forceinline__ float fdot2_sw(h2 a, h2 b, float c) {
    return c + (float)a.x * (float)b.x + (float)a.y * (float)b.y;
}
# define FDOT2(a,b,c) fdot2_sw((a),(b),(c))
#endif

// Degree-6 truncated Chebyshev approx of e^x on [-2,2] in t=x/2 (power basis).
constexpr float ACOEF_C[7] = {0.99994459f, 2.00308514f, 2.00174650f,
                              1.30890404f, 0.65803033f, 0.31441604f, 0.10241921f};

constexpr int mono_e(int idx) {
    int i = 0;
    for (int e0 = 0; e0 <= DEG; ++e0)
        for (int e1 = 0; e1 <= DEG - e0; ++e1)
            for (int e2 = 0; e2 <= DEG - e0 - e1; ++e2)
                for (int e3 = 0; e3 <= DEG - e0 - e1 - e2; ++e3) {
                    if (i == idx) return (e0 << 12) | (e1 << 8) | (e2 << 4) | e3;
                    ++i;
                }
    return 0;
}
constexpr float mfact(int n) { float r = 1.f; for (int i = 2; i <= n; ++i) r *= (float)i; return r; }
constexpr float mono_c(int idx) {
    const int E = mono_e(idx);
    const int e0 = E >> 12, e1 = (E >> 8) & 15, e2 = (E >> 4) & 15, e3 = E & 15;
    const int d = e0 + e1 + e2 + e3;
    return ACOEF_C[d] * (mfact(d) / (mfact(e0) * mfact(e1) * mfact(e2) * mfact(e3)));
}

template <int BEG, class F, int... Is>
__device__ __forceinline__ void sf_impl(F f, std::integer_sequence<int, Is...>) {
    (f(std::integral_constant<int, BEG + Is>{}), ...);
}
template <int BEG, int END, class F>
__device__ __forceinline__ void static_for(F f) {
    sf_impl<BEG>(f, std::make_integer_sequence<int, END - BEG>{});
}

// ---------------- K1: per-64-key-chunk partial moments (r6, known-good) ----
template <int BEG, int END>
__device__ __forceinline__ void phi_body(_Float16* __restrict__ Phi, int lane,
                                         const float (&pw0)[7], const float (&pw1)[7],
                                         const float (&pw2)[7], const float (&pw3)[7]) {
    static_for<BEG, END>([&](auto Ic) {
        constexpr int idx = Ic.value;
        constexpr int E = mono_e(idx);
        constexpr float C = mono_c(idx);
        const float v = C * (pw0[E >> 12] * pw1[(E >> 8) & 15]) *
                            (pw2[(E >> 4) & 15] * pw3[E & 15]);
        Phi[idx * PHI_LD + lane] = (_Float16)v;
    });
}

__global__ __launch_bounds__(256, 4)
void k1_moments(const float* __restrict__ x, const float* __restrict__ theta_rx,
                float* __restrict__ ws) {
    __shared__ _Float16 Phi[NMONO * PHI_LD];          // 27.7 KB
    __shared__ __align__(16) _Float16 kvh[KPB / 2][8];
    __shared__ float th_s[8];

    const int t = threadIdx.x, bid = blockIdx.x;
    const int kc = bid & 31, h = (bid >> 5) & 1, b = bid >> 6;

    if (t < 8) th_s[t] = theta_rx[t];
    __syncthreads();

    const int lane = t & 63, wq = t >> 6;
    {
        const float* xr = x + ((size_t)b * NS + kc * KPB + lane) * NE;
        const float4 v0 = *reinterpret_cast<const float4*>(xr);
        const float4 v1 = *reinterpret_cast<const float4*>(xr + 4);
        const float c0 = __cosf(v0.x + th_s[0]), c1 = __cosf(v0.y + th_s[1]);
        const float c2 = __cosf(v0.z + th_s[2]), c3 = __cosf(v0.w + th_s[3]);
        const float c4 = __cosf(v1.x + th_s[4]), c5 = __cosf(v1.y + th_s[5]);
        const float c6 = __cosf(v1.z + th_s[6]), c7 = __cosf(v1.w + th_s[7]);
        const float p1 = c0*c1, p2 = p1*c2, p3 = p2*c3, p4 = p3*c4;
        const float p5 = p4*c5, p6 = p5*c6, p7 = p6*c7;
        float k0, k1v, k2v, k3v;
        if (h == 0) {
            const float s6 = c7*c6, s5 = s6*c5, s4 = s5*c4, s3 = s4*c3, s2 = s3*c2;
            k0 = s2*c1; k1v = p1; k2v = p2; k3v = p3;
        } else {
            k0 = p4; k1v = p5; k2v = p6; k3v = p7;
        }
        if (t < 64) {
            const int j = t >> 1, par = t & 1;
            kvh[j][0 + par] = (_Float16)k0;  kvh[j][2 + par] = (_Float16)k1v;
            kvh[j][4 + par] = (_Float16)k2v; kvh[j][6 + par] = (_Float16)k3v;
        }
        float pw0[7], pw1[7], pw2[7], pw3[7];
        pw0[0] = pw1[0] = pw2[0] = pw3[0] = 1.f;
        #pragma unroll
        for (int i = 1; i <= DEG; ++i) {
            pw0[i] = pw0[i-1] * k0;  pw1[i] = pw1[i-1] * k1v;
            pw2[i] = pw2[i-1] * k2v; pw3[i] = pw3[i-1] * k3v;
        }
        switch (wq) {   // wave-uniform: each wave builds its quarter of Phi
            case 0: phi_body<0,   53 >(Phi, lane, pw0, pw1, pw2, pw3); break;
            case 1: phi_body<53,  106>(Phi, lane, pw0, pw1, pw2, pw3); break;
            case 2: phi_body<106, 159>(Phi, lane, pw0, pw1, pw2, pw3); break;
            default: phi_body<159, 210>(Phi, lane, pw0, pw1, pw2, pw3); break;
        }
    }
    __syncthreads();

    if (t < NMONO) {
        const h2 one2 = {(_Float16)1.f, (_Float16)1.f};
        float a0 = 0.f, a1 = 0.f, a2 = 0.f, a3 = 0.f, a4 = 0.f;
        #pragma unroll 8
        for (int j = 0; j < KPB / 2; ++j) {
            const h2 phi2 = *reinterpret_cast<const h2*>(&Phi[t * PHI_LD + 2 * j]);
            const float4 kv4 = *reinterpret_cast<const float4*>(&kvh[j][0]);
            const h2 kA = __builtin_bit_cast(h2, kv4.x);
            const h2 kB = __builtin_bit_cast(h2, kv4.y);
            const h2 kC = __builtin_bit_cast(h2, kv4.z);
            const h2 kD = __builtin_bit_cast(h2, kv4.w);
            a0 = FDOT2(phi2, kA, a0);
            a1 = FDOT2(phi2, kB, a1);
            a2 = FDOT2(phi2, kC, a2);
            a3 = FDOT2(phi2, kD, a3);
            a4 = FDOT2(phi2, one2, a4);
        }
        float* dst = ws + (size_t)bid * PART_STRIDE;
        dst[0 * NMONO + t] = a0;
        dst[1 * NMONO + t] = a1;
        dst[2 * NMONO + t] = a2;
        dst[3 * NMONO + t] = a3;
        dst[4 * NMONO + t] = a4;
    }
}

// ---------------- K2: reduce + queries + fused epilogue (wave-filled) ----
template <int BEG, int END>
__device__ __forceinline__ void p2_body2(const float4* __restrict__ Mn,
                                         const float* __restrict__ Md, int base,
                                         const float (&pwA)[4][7], const float (&pwB)[4][7],
                                         f32x2& a01A, f32x2& a23A, float& adA,
                                         f32x2& a01B, f32x2& a23B, float& adB) {
    static_for<BEG, END>([&](auto Ic) {
        constexpr int idx = Ic.value;
        constexpr int E = mono_e(idx);
        constexpr int e0 = E >> 12, e1 = (E >> 8) & 15, e2 = (E >> 4) & 15, e3 = E & 15;
        const float4 mv = Mn[base + idx];     // wave-uniform broadcast
        const float  md = Md[base + idx];
        const f32x2 m01 = {mv.x, mv.y}, m23 = {mv.z, mv.w};
        const float PA = (pwA[0][e0] * pwA[1][e1]) * (pwA[2][e2] * pwA[3][e3]);
        const float PB = (pwB[0][e0] * pwB[1][e1]) * (pwB[2][e2] * pwB[3][e3]);
        a01A += PA * m01;  a23A += PA * m23;  adA += PA * md;
        a01B += PB * m01;  a23B += PB * m23;  adB += PB * md;
    });
}

__global__ __launch_bounds__(1024)
void k2_main(const float* __restrict__ x, const float* __restrict__ theta_rx,
             const float* __restrict__ w_out, const float* __restrict__ theta_ry,
             const float* __restrict__ w1, const float* __restrict__ b1,
             const float* __restrict__ w2, const float* __restrict__ b2,
             const float* __restrict__ g1, const float* __restrict__ be1,
             const float* __restrict__ g2, const float* __restrict__ be2,
             const float* __restrict__ ws, float* __restrict__ out) {
    __shared__ float4 Mn_lds[2 * NMONO];       // 6.7 KB
    __shared__ float  Md_lds[2 * NMONO];       // 1.7 KB
    __shared__ float  z_c[8][QPB];             // 4 KB
    __shared__ float  x1_c[8][QPB];            // 4 KB
    __shared__ float  zf_c[8][QPB];            // 4 KB
    __shared__ float  part_a[4][256][5];       // 20.5 KB (also R1 reduce scratch)
    __shared__ float  w1_s[NF][NE];            // 16 KB
    __shared__ float  w2t_s[NF][NE];           // 16 KB
    __shared__ float  b1_s[NF];                // 2 KB
    __shared__ float  wout_s[NE][NE];
    __shared__ float  cry_s[8], g1_s[8], be1_s[8], g2_s[8], be2_s[8], b2_s[8];
    // total ~77 KB

    const int t = threadIdx.x, bid = blockIdx.x;
    const int b = bid >> 4, qc = bid & 15;

    float (*scr)[5] = (float(*)[5])&part_a[0][0][0];   // 840x5 fits in part_a

    // ---- R1: stage weights + partial PART reduce (16 chunks each) + z rows ----
    for (int i = t; i < NF * NE; i += 1024) {
        ((float*)w1_s)[i] = w1[i];
        const int e = i >> 9, f = i & (NF - 1);
        w2t_s[f][e] = w2[i];
    }
    if (t < NF) b1_s[t] = b1[t];
    if (t < NE * NE) ((float*)wout_s)[t] = w_out[t];
    if (t < 8) {
        cry_s[t] = __cosf(theta_ry[t]);
        g1_s[t]  = g1[t];  be1_s[t] = be1[t];
        g2_s[t]  = g2[t];  be2_s[t] = be2[t];
        b2_s[t]  = b2[t];
    }
    if (t < 840) {                      // partial reduce: (half, h, a)
        const int half = t / 420;
        const int a2 = t - half * 420;
        const int h = (a2 >= NMONO) ? 1 : 0;
        const int a = a2 - h * NMONO;
        const float* src = ws + (size_t)((b * 2 + h) * NCHUNK + half * 16) * PART_STRIDE;
        float s0 = 0.f, s1 = 0.f, s2 = 0.f, s3 = 0.f, s4 = 0.f;
        #pragma unroll 4
        for (int kc = 0; kc < 16; ++kc) {
            const float* p = src + (size_t)kc * PART_STRIDE;
            s0 += p[0 * NMONO + a]; s1 += p[1 * NMONO + a];
            s2 += p[2 * NMONO + a]; s3 += p[3 * NMONO + a];
            s4 += p[4 * NMONO + a];
        }
        float* d = scr[t];
        d[0] = s0; d[1] = s1; d[2] = s2; d[3] = s3; d[4] = s4;
    }
    if (t >= 896) {                     // z for the 128 query rows
        const int r = t - 896;
        const float* xr = x + ((size_t)b * NS + qc * QPB + r) * NE;
        const float4 v0 = *reinterpret_cast<const float4*>(xr);
        const float4 v1 = *reinterpret_cast<const float4*>(xr + 4);
        const float4 ta = *reinterpret_cast<const float4*>(theta_rx);
        const float4 tb = *reinterpret_cast<const float4*>(theta_rx + 4);
        const float c0 = __cosf(v0.x + ta.x), c1 = __cosf(v0.y + ta.y);
        const float c2 = __cosf(v0.z + ta.z), c3 = __cosf(v0.w + ta.w);
        const float c4 = __cosf(v1.x + tb.x), c5 = __cosf(v1.y + tb.y);
        const float c6 = __cosf(v1.z + tb.z), c7 = __cosf(v1.w + tb.w);
        const float p1 = c0*c1, p2 = p1*c2, p3 = p2*c3, p4 = p3*c4;
        const float p5 = p4*c5, p6 = p5*c6, p7 = p6*c7;
        const float s6 = c7*c6, s5 = s6*c5, s4 = s5*c4, s3 = s4*c3, s2 = s3*c2;
        z_c[0][r] = s2*c1; z_c[1][r] = p1; z_c[2][r] = p2; z_c[3][r] = p3;
        z_c[4][r] = p4;    z_c[5][r] = p5; z_c[6][r] = p6; z_c[7][r] = p7;
    }
    __syncthreads();

    // ---- R2: combine the two 16-chunk halves -> moments ----
    if (t < 2 * NMONO) {
        const float* pa = scr[t];
        const float* pb = scr[t + 420];
        Mn_lds[t] = make_float4(pa[0] + pb[0], pa[1] + pb[1],
                                pa[2] + pb[2], pa[3] + pb[3]);
        Md_lds[t] = pa[4] + pb[4];
    }
    __syncthreads();

    // ---- P2: 8 waves, wave = (g,h), 2 rows per lane ----
    if (t < 512) {
        const int w = t >> 6, l = t & 63;
        const int g = w >> 1, h = w & 1;
        const int rA = l, rB = l + 64;
        float pwA[4][7], pwB[4][7];
        #pragma unroll
        for (int d = 0; d < 4; ++d) {
            const float uA = z_c[h*4+d][rA] * 0.25f;
            const float uB = z_c[h*4+d][rB] * 0.25f;
            pwA[d][0] = 1.f; pwB[d][0] = 1.f;
            #pragma unroll
            for (int i = 1; i <= DEG; ++i) {
                pwA[d][i] = pwA[d][i-1] * uA;
                pwB[d][i] = pwB[d][i-1] * uB;
            }
        }
        f32x2 a01A = {0.f,0.f}, a23A = {0.f,0.f}, a01B = {0.f,0.f}, a23B = {0.f,0.f};
        float adA = 0.f, adB = 0.f;
        const int base = h * NMONO;
        switch (g) {
            case 0: p2_body2<0,   53 >(Mn_lds, Md_lds, base, pwA, pwB, a01A, a23A, adA, a01B, a23B, adB); break;
            case 1: p2_body2<53,  106>(Mn_lds, Md_lds, base, pwA, pwB, a01A, a23A, adA, a01B, a23B, adB); break;
            case 2: p2_body2<106, 159>(Mn_lds, Md_lds, base, pwA, pwB, a01A, a23A, adA, a01B, a23B, adB); break;
            default: p2_body2<159, 210>(Mn_lds, Md_lds, base, pwA, pwB, a01A, a23A, adA, a01B, a23B, adB); break;
        }
        float* pa = &part_a[g][h * 128 + rA][0];
        pa[0] = a01A.x; pa[1] = a01A.y; pa[2] = a23A.x; pa[3] = a23A.y; pa[4] = adA;
        float* pb = &part_a[g][h * 128 + rB][0];
        pb[0] = a01B.x; pb[1] = a01B.y; pb[2] = a23B.x; pb[3] = a23B.y; pb[4] = adB;
    }
    __syncthreads();

    // ---- P34: combine groups -> attn -> out_proj -> LN1 -> zf (128 thr) ----
    if (t < QPB) {
        float av[NE];
        #pragma unroll
        for (int h = 0; h < 2; ++h) {
            float n0 = 0.f, n1 = 0.f, n2 = 0.f, n3 = 0.f, dd = 0.f;
            #pragma unroll
            for (int g = 0; g < 4; ++g) {
                const float* pa = &part_a[g][h * 128 + t][0];
                n0 += pa[0]; n1 += pa[1]; n2 += pa[2]; n3 += pa[3]; dd += pa[4];
            }
            const float inv = 1.0f / dd;
            av[h*4+0] = n0 * inv; av[h*4+1] = n1 * inv;
            av[h*4+2] = n2 * inv; av[h*4+3] = n3 * inv;
        }
        float y[NE];
        #pragma unroll
        for (int e = 0; e < NE; ++e) {
            float acc = 0.f;
            #pragma unroll
            for (int k = 0; k < NE; ++k) acc += av[k] * wout_s[e][k];
            y[e] = acc;
        }
        const float* xr = x + ((size_t)b * NS + qc * QPB + t) * NE;
        const float4 xv0 = *reinterpret_cast<const float4*>(xr);
        const float4 xv1 = *reinterpret_cast<const float4*>(xr + 4);
        float t1[NE];
        t1[0] = xv0.x + y[0]; t1[1] = xv0.y + y[1]; t1[2] = xv0.z + y[2]; t1[3] = xv0.w + y[3];
        t1[4] = xv1.x + y[4]; t1[5] = xv1.y + y[5]; t1[6] = xv1.z + y[6]; t1[7] = xv1.w + y[7];
        float mu = 0.f;
        #pragma unroll
        for (int e = 0; e < NE; ++e) mu += t1[e];
        mu *= 0.125f;
        float var = 0.f;
        #pragma unroll
        for (int e = 0; e < NE; ++e) { const float d = t1[e] - mu; var += d * d; }
        var *= 0.125f;
        const float inv1 = rsqrtf(var + LNEPS);
        #pragma unroll
        for (int e = 0; e < NE; ++e) {
            const float x1e = (t1[e] - mu) * inv1 * g1_s[e] + be1_s[e];
            x1_c[e][t] = x1e;
            zf_c[e][t] = cry_s[e] * __cosf(x1e);
        }
    }
    __syncthreads();

    // ---- P5: FFN with ALL 1024 threads (row = t>>3, f-split = t&7),
    //      shfl-butterfly reduce, LN2 + store inline ----
    {
        const int r = t >> 3, sub = t & 7;
        float zf[NE];
        #pragma unroll
        for (int e = 0; e < NE; ++e) zf[e] = zf_c[e][r];
        f32x2 a01 = {0.f,0.f}, a23 = {0.f,0.f}, a45 = {0.f,0.f}, a67 = {0.f,0.f};
        #pragma unroll 8
        for (int i = 0; i < 64; ++i) {
            const int f = sub + (i << 3);
            const float4 wa = *reinterpret_cast<const float4*>(&w1_s[f][0]);
            const float4 wb = *reinterpret_cast<const float4*>(&w1_s[f][4]);
            float hv = b1_s[f] + zf[0]*wa.x + zf[1]*wa.y + zf[2]*wa.z + zf[3]*wa.w
                               + zf[4]*wb.x + zf[5]*wb.y + zf[6]*wb.z + zf[7]*wb.w;
            hv = fmaxf(hv, 0.f);
            const float4 ua = *reinterpret_cast<const float4*>(&w2t_s[f][0]);
            const float4 ub = *reinterpret_cast<const float4*>(&w2t_s[f][4]);
            a01 += hv * (f32x2){ua.x, ua.y};
            a23 += hv * (f32x2){ua.z, ua.w};
            a45 += hv * (f32x2){ub.x, ub.y};
            a67 += hv * (f32x2){ub.z, ub.w};
        }
        float acc[NE] = {a01.x, a01.y, a23.x, a23.y, a45.x, a45.y, a67.x, a67.y};
        #pragma unroll
        for (int m = 1; m < 8; m <<= 1) {
            #pragma unroll
            for (int e = 0; e < NE; ++e) acc[e] += __shfl_xor(acc[e], m, 64);
        }
        float t2[NE];
        #pragma unroll
        for (int e = 0; e < NE; ++e) t2[e] = x1_c[e][r] + acc[e] + b2_s[e];
        float mu = 0.f;
        #pragma unroll
        for (int e = 0; e < NE; ++e) mu += t2[e];
        mu *= 0.125f;
        float var = 0.f;
        #pragma unroll
        for (int e = 0; e < NE; ++e) { const float d = t2[e] - mu; var += d * d; }
        var *= 0.125f;
        const float inv2 = rsqrtf(var + LNEPS);
        out[((size_t)b * NS + qc * QPB + r) * NE + sub] =
            (t2[sub] - mu) * inv2 * g2_s[sub] + be2_s[sub];
    }
}

extern "C" void kernel_launch(void* const* d_in, const int* in_sizes, int n_in,
                              void* d_out, int out_size, void* d_ws, size_t ws_size,
                              hipStream_t stream) {
    const float* x        = (const float*)d_in[0];
    const float* theta_rx = (const float*)d_in[1];
    const float* w_out    = (const float*)d_in[2];
    const float* theta_ry = (const float*)d_in[3];
    const float* w1       = (const float*)d_in[4];
    const float* b1       = (const float*)d_in[5];
    const float* w2       = (const float*)d_in[6];
    const float* b2       = (const float*)d_in[7];
    const float* g1       = (const float*)d_in[8];
    const float* be1      = (const float*)d_in[9];
    const float* g2       = (const float*)d_in[10];
    const float* be2      = (const float*)d_in[11];
    float* out = (float*)d_out;
    float* ws  = (float*)d_ws;

    k1_moments<<<dim3(NB * NH * NCHUNK), dim3(256), 0, stream>>>(x, theta_rx, ws);
    k2_main<<<dim3(NB * (NS / QPB)), dim3(1024), 0, stream>>>(
        x, theta_rx, w_out, theta_ry, w1, b1, w2, b2, g1, be1, g2, be2, ws, out);
}

// Round 13
// 35.870 us; speedup vs baseline: 1.6872x; 1.6872x over previous
//
#include <hip/hip_runtime.h>
#include <math.h>
#include <utility>

#define NB 16
#define NS 2048
#define NE 8
#define NH 2
#define NF 512
#define DEG 6
#define NMONO 210          // #monomials in 4 vars, total degree <= 6
#define KPB 64             // keys per k1 block
#define NCHUNK 32          // key chunks per (b,h)
#define PHI_LD 66          // fp16 row stride (64 keys + 2 pad)
#define QPB 128
#define LNEPS 1e-5f
#define PART_STRIDE (5 * NMONO)

typedef float f32x2 __attribute__((ext_vector_type(2)));
typedef _Float16 h2 __attribute__((ext_vector_type(2)));

#if defined(__has_builtin)
# if __has_builtin(__builtin_amdgcn_fdot2)
#  define FDOT2(a,b,c) __builtin_amdgcn_fdot2((a),(b),(c),false)
# endif
#endif
#ifndef FDOT2
static __device__ __forceinline__ float fdot2_sw(h2 a, h2 b, float c) {
    return c + (float)a.x * (float)b.x + (float)a.y * (float)b.y;
}
# define FDOT2(a,b,c) fdot2_sw((a),(b),(c))
#endif

// Degree-6 truncated Chebyshev approx of e^x on [-2,2] in t=x/2 (power basis).
constexpr float ACOEF_C[7] = {0.99994459f, 2.00308514f, 2.00174650f,
                              1.30890404f, 0.65803033f, 0.31441604f, 0.10241921f};

constexpr int mono_e(int idx) {
    int i = 0;
    for (int e0 = 0; e0 <= DEG; ++e0)
        for (int e1 = 0; e1 <= DEG - e0; ++e1)
            for (int e2 = 0; e2 <= DEG - e0 - e1; ++e2)
                for (int e3 = 0; e3 <= DEG - e0 - e1 - e2; ++e3) {
                    if (i == idx) return (e0 << 12) | (e1 << 8) | (e2 << 4) | e3;
                    ++i;
                }
    return 0;
}
constexpr float mfact(int n) { float r = 1.f; for (int i = 2; i <= n; ++i) r *= (float)i; return r; }
constexpr float mono_c(int idx) {
    const int E = mono_e(idx);
    const int e0 = E >> 12, e1 = (E >> 8) & 15, e2 = (E >> 4) & 15, e3 = E & 15;
    const int d = e0 + e1 + e2 + e3;
    return ACOEF_C[d] * (mfact(d) / (mfact(e0) * mfact(e1) * mfact(e2) * mfact(e3)));
}

template <int BEG, class F, int... Is>
__device__ __forceinline__ void sf_impl(F f, std::integer_sequence<int, Is...>) {
    (f(std::integral_constant<int, BEG + Is>{}), ...);
}
template <int BEG, int END, class F>
__device__ __forceinline__ void static_for(F f) {
    sf_impl<BEG>(f, std::make_integer_sequence<int, END - BEG>{});
}

// ---------------- K1: per-64-key-chunk partial moments (r6, known-good) ----
template <int BEG, int END>
__device__ __forceinline__ void phi_body(_Float16* __restrict__ Phi, int lane,
                                         const float (&pw0)[7], const float (&pw1)[7],
                                         const float (&pw2)[7], const float (&pw3)[7]) {
    static_for<BEG, END>([&](auto Ic) {
        constexpr int idx = Ic.value;
        constexpr int E = mono_e(idx);
        constexpr float C = mono_c(idx);
        const float v = C * (pw0[E >> 12] * pw1[(E >> 8) & 15]) *
                            (pw2[(E >> 4) & 15] * pw3[E & 15]);
        Phi[idx * PHI_LD + lane] = (_Float16)v;
    });
}

__global__ __launch_bounds__(256, 4)
void k1_moments(const float* __restrict__ x, const float* __restrict__ theta_rx,
                float* __restrict__ ws) {
    __shared__ _Float16 Phi[NMONO * PHI_LD];          // 27.7 KB
    __shared__ __align__(16) _Float16 kvh[KPB / 2][8];
    __shared__ float th_s[8];

    const int t = threadIdx.x, bid = blockIdx.x;
    const int kc = bid & 31, h = (bid >> 5) & 1, b = bid >> 6;

    if (t < 8) th_s[t] = theta_rx[t];
    __syncthreads();

    const int lane = t & 63, wq = t >> 6;
    {
        const float* xr = x + ((size_t)b * NS + kc * KPB + lane) * NE;
        const float4 v0 = *reinterpret_cast<const float4*>(xr);
        const float4 v1 = *reinterpret_cast<const float4*>(xr + 4);
        const float c0 = __cosf(v0.x + th_s[0]), c1 = __cosf(v0.y + th_s[1]);
        const float c2 = __cosf(v0.z + th_s[2]), c3 = __cosf(v0.w + th_s[3]);
        const float c4 = __cosf(v1.x + th_s[4]), c5 = __cosf(v1.y + th_s[5]);
        const float c6 = __cosf(v1.z + th_s[6]), c7 = __cosf(v1.w + th_s[7]);
        const float p1 = c0*c1, p2 = p1*c2, p3 = p2*c3, p4 = p3*c4;
        const float p5 = p4*c5, p6 = p5*c6, p7 = p6*c7;
        float k0, k1v, k2v, k3v;
        if (h == 0) {
            const float s6 = c7*c6, s5 = s6*c5, s4 = s5*c4, s3 = s4*c3, s2 = s3*c2;
            k0 = s2*c1; k1v = p1; k2v = p2; k3v = p3;
        } else {
            k0 = p4; k1v = p5; k2v = p6; k3v = p7;
        }
        if (t < 64) {
            const int j = t >> 1, par = t & 1;
            kvh[j][0 + par] = (_Float16)k0;  kvh[j][2 + par] = (_Float16)k1v;
            kvh[j][4 + par] = (_Float16)k2v; kvh[j][6 + par] = (_Float16)k3v;
        }
        float pw0[7], pw1[7], pw2[7], pw3[7];
        pw0[0] = pw1[0] = pw2[0] = pw3[0] = 1.f;
        #pragma unroll
        for (int i = 1; i <= DEG; ++i) {
            pw0[i] = pw0[i-1] * k0;  pw1[i] = pw1[i-1] * k1v;
            pw2[i] = pw2[i-1] * k2v; pw3[i] = pw3[i-1] * k3v;
        }
        switch (wq) {   // wave-uniform: each wave builds its quarter of Phi
            case 0: phi_body<0,   53 >(Phi, lane, pw0, pw1, pw2, pw3); break;
            case 1: phi_body<53,  106>(Phi, lane, pw0, pw1, pw2, pw3); break;
            case 2: phi_body<106, 159>(Phi, lane, pw0, pw1, pw2, pw3); break;
            default: phi_body<159, 210>(Phi, lane, pw0, pw1, pw2, pw3); break;
        }
    }
    __syncthreads();

    if (t < NMONO) {
        const h2 one2 = {(_Float16)1.f, (_Float16)1.f};
        float a0 = 0.f, a1 = 0.f, a2 = 0.f, a3 = 0.f, a4 = 0.f;
        #pragma unroll 8
        for (int j = 0; j < KPB / 2; ++j) {
            const h2 phi2 = *reinterpret_cast<const h2*>(&Phi[t * PHI_LD + 2 * j]);
            const float4 kv4 = *reinterpret_cast<const float4*>(&kvh[j][0]);
            const h2 kA = __builtin_bit_cast(h2, kv4.x);
            const h2 kB = __builtin_bit_cast(h2, kv4.y);
            const h2 kC = __builtin_bit_cast(h2, kv4.z);
            const h2 kD = __builtin_bit_cast(h2, kv4.w);
            a0 = FDOT2(phi2, kA, a0);
            a1 = FDOT2(phi2, kB, a1);
            a2 = FDOT2(phi2, kC, a2);
            a3 = FDOT2(phi2, kD, a3);
            a4 = FDOT2(phi2, one2, a4);
        }
        float* dst = ws + (size_t)bid * PART_STRIDE;
        dst[0 * NMONO + t] = a0;
        dst[1 * NMONO + t] = a1;
        dst[2 * NMONO + t] = a2;
        dst[3 * NMONO + t] = a3;
        dst[4 * NMONO + t] = a4;
    }
}

// ---------------- K2: r6 structure, spill-free P2, 128-VGPR budget ----------
template <int BEG, int END>
__device__ __forceinline__ void p2_body1(const float4* __restrict__ Mn,
                                         const float* __restrict__ Md, int base,
                                         const float (&pw)[4][7],
                                         f32x2& a01, f32x2& a23, float& ad) {
    static_for<BEG, END>([&](auto Ic) {
        constexpr int idx = Ic.value;
        constexpr int E = mono_e(idx);
        constexpr int e0 = E >> 12, e1 = (E >> 8) & 15, e2 = (E >> 4) & 15, e3 = E & 15;
        const float4 mv = Mn[base + idx];     // wave-uniform broadcast
        const float  md = Md[base + idx];
        const float P = (pw[0][e0] * pw[1][e1]) * (pw[2][e2] * pw[3][e3]);
        a01 += P * (f32x2){mv.x, mv.y};
        a23 += P * (f32x2){mv.z, mv.w};
        ad  += P * md;
    });
}

__global__ __launch_bounds__(1024, 4)   // 4 waves/EU = 1 block/CU -> 128 VGPR cap
void k2_main(const float* __restrict__ x, const float* __restrict__ theta_rx,
             const float* __restrict__ w_out, const float* __restrict__ theta_ry,
             const float* __restrict__ w1, const float* __restrict__ b1,
             const float* __restrict__ w2, const float* __restrict__ b2,
             const float* __restrict__ g1, const float* __restrict__ be1,
             const float* __restrict__ g2, const float* __restrict__ be2,
             const float* __restrict__ ws, float* __restrict__ out) {
    __shared__ float4 Mn_lds[2 * NMONO];
    __shared__ float  Md_lds[2 * NMONO];
    __shared__ float  z_c[8][QPB];
    __shared__ float  x1_c[8][QPB];
    __shared__ float  zf_c[8][QPB];            // later reused for t2
    __shared__ float  attn_c[8][QPB];
    __shared__ float  part_a[4][256][5];
    __shared__ float  part_f[8][QPB][9];       // [fsplit][row][e], pad 9 -> conflict-free
    __shared__ float  w1_s[NF][NE];
    __shared__ float  w2t_s[NF][NE];
    __shared__ float  b1_s[NF];
    __shared__ float  wout_s[NE][NE];
    __shared__ float  th_s[8], cry_s[8], g1_s[8], be1_s[8], g2_s[8], be2_s[8], b2_s[8];

    const int t = threadIdx.x, bid = blockIdx.x;
    const int b = bid >> 4, qc = bid & 15;

    // ---- reduce PART (32 chunks) -> moments in LDS ----
    if (t < 2 * NMONO) {
        const int h = (t >= NMONO) ? 1 : 0;
        const int a = t - h * NMONO;
        const float* src = ws + (size_t)((b * 2 + h) * NCHUNK) * PART_STRIDE;
        float s0 = 0.f, s1 = 0.f, s2 = 0.f, s3 = 0.f, s4 = 0.f;
        #pragma unroll 4
        for (int kc = 0; kc < NCHUNK; ++kc) {
            const float* p = src + (size_t)kc * PART_STRIDE;
            s0 += p[0 * NMONO + a]; s1 += p[1 * NMONO + a];
            s2 += p[2 * NMONO + a]; s3 += p[3 * NMONO + a];
            s4 += p[4 * NMONO + a];
        }
        Mn_lds[t] = make_float4(s0, s1, s2, s3);
        Md_lds[t] = s4;
    }

    // ---- stage weights ----
    for (int i = t; i < NF * NE; i += 1024) {
        ((float*)w1_s)[i] = w1[i];
        const int e = i >> 9, f = i & (NF - 1);
        w2t_s[f][e] = w2[i];
    }
    if (t < NF) b1_s[t] = b1[t];
    if (t < NE * NE) ((float*)wout_s)[t] = w_out[t];
    if (t < 8) {
        th_s[t]  = theta_rx[t];
        cry_s[t] = __cosf(theta_ry[t]);
        g1_s[t]  = g1[t];  be1_s[t] = be1[t];
        g2_s[t]  = g2[t];  be2_s[t] = be2[t];
        b2_s[t]  = b2[t];
    }
    __syncthreads();

    // ---- P1: z for the 128 query rows ----
    if (t < QPB) {
        const float* xr = x + ((size_t)b * NS + qc * QPB + t) * NE;
        const float4 v0 = *reinterpret_cast<const float4*>(xr);
        const float4 v1 = *reinterpret_cast<const float4*>(xr + 4);
        const float c0 = __cosf(v0.x + th_s[0]), c1 = __cosf(v0.y + th_s[1]);
        const float c2 = __cosf(v0.z + th_s[2]), c3 = __cosf(v0.w + th_s[3]);
        const float c4 = __cosf(v1.x + th_s[4]), c5 = __cosf(v1.y + th_s[5]);
        const float c6 = __cosf(v1.z + th_s[6]), c7 = __cosf(v1.w + th_s[7]);
        const float p1 = c0*c1, p2 = p1*c2, p3 = p2*c3, p4 = p3*c4;
        const float p5 = p4*c5, p6 = p5*c6, p7 = p6*c7;
        const float s6 = c7*c6, s5 = s6*c5, s4 = s5*c4, s3 = s4*c3, s2 = s3*c2;
        z_c[0][t] = s2*c1; z_c[1][t] = p1; z_c[2][t] = p2; z_c[3][t] = p3;
        z_c[4][t] = p4;    z_c[5][t] = p5; z_c[6][t] = p6; z_c[7][t] = p7;
    }
    __syncthreads();

    // ---- P2: 16 waves, wave = (g, h, r-half), ONE row per lane (no spills) ----
    {
        const int w = t >> 6, lane = t & 63;
        const int g = w & 3;                 // monomial group (wave-uniform)
        const int h = (w >> 3) & 1;          // head (wave-uniform)
        const int r = ((w >> 2) & 1) * 64 + lane;
        float pw[4][7];
        #pragma unroll
        for (int d = 0; d < 4; ++d) {
            const float u = z_c[h*4+d][r] * 0.25f;
            pw[d][0] = 1.f;
            #pragma unroll
            for (int i = 1; i <= DEG; ++i) pw[d][i] = pw[d][i-1] * u;
        }
        f32x2 a01 = {0.f,0.f}, a23 = {0.f,0.f};
        float ad = 0.f;
        const int base = h * NMONO;
        switch (g) {   // wave-uniform branch
            case 0: p2_body1<0,   53 >(Mn_lds, Md_lds, base, pw, a01, a23, ad); break;
            case 1: p2_body1<53,  106>(Mn_lds, Md_lds, base, pw, a01, a23, ad); break;
            case 2: p2_body1<106, 159>(Mn_lds, Md_lds, base, pw, a01, a23, ad); break;
            default: p2_body1<159, 210>(Mn_lds, Md_lds, base, pw, a01, a23, ad); break;
        }
        float* pa = &part_a[g][h * 128 + r][0];
        pa[0] = a01.x; pa[1] = a01.y; pa[2] = a23.x; pa[3] = a23.y; pa[4] = ad;
    }
    __syncthreads();

    // ---- P3: combine groups, normalize ----
    if (t < 256) {
        const int h = t >> 7, r = t & 127;
        float n0 = 0.f, n1 = 0.f, n2 = 0.f, n3 = 0.f, dd = 0.f;
        #pragma unroll
        for (int g = 0; g < 4; ++g) {
            const float* pa = &part_a[g][t][0];
            n0 += pa[0]; n1 += pa[1]; n2 += pa[2]; n3 += pa[3]; dd += pa[4];
        }
        const float inv = 1.0f / dd;
        attn_c[h*4+0][r] = n0 * inv; attn_c[h*4+1][r] = n1 * inv;
        attn_c[h*4+2][r] = n2 * inv; attn_c[h*4+3][r] = n3 * inv;
    }
    __syncthreads();

    // ---- P4: out_proj -> LN1 -> zf ----
    if (t < QPB) {
        float av[NE];
        #pragma unroll
        for (int e = 0; e < NE; ++e) av[e] = attn_c[e][t];
        float y[NE];
        #pragma unroll
        for (int e = 0; e < NE; ++e) {
            float acc = 0.f;
            #pragma unroll
            for (int k = 0; k < NE; ++k) acc += av[k] * wout_s[e][k];
            y[e] = acc;
        }
        const float* xr = x + ((size_t)b * NS + qc * QPB + t) * NE;
        const float4 xv0 = *reinterpret_cast<const float4*>(xr);
        const float4 xv1 = *reinterpret_cast<const float4*>(xr + 4);
        float t1[NE];
        t1[0] = xv0.x + y[0]; t1[1] = xv0.y + y[1]; t1[2] = xv0.z + y[2]; t1[3] = xv0.w + y[3];
        t1[4] = xv1.x + y[4]; t1[5] = xv1.y + y[5]; t1[6] = xv1.z + y[6]; t1[7] = xv1.w + y[7];
        float mu = 0.f;
        #pragma unroll
        for (int e = 0; e < NE; ++e) mu += t1[e];
        mu *= 0.125f;
        float var = 0.f;
        #pragma unroll
        for (int e = 0; e < NE; ++e) { const float d = t1[e] - mu; var += d * d; }
        var *= 0.125f;
        const float inv1 = rsqrtf(var + LNEPS);
        #pragma unroll
        for (int e = 0; e < NE; ++e) {
            const float x1e = (t1[e] - mu) * inv1 * g1_s[e] + be1_s[e];
            x1_c[e][t] = x1e;
            zf_c[e][t] = cry_s[e] * __cosf(x1e);
        }
    }
    __syncthreads();

    // ---- P5: FFN, 256 threads, 4 rows/thread ----
    if (t < 256) {
        const int fs = t >> 5;
        const int rr = t & 31;
        f32x2 zf01[4], zf23[4], zf45[4], zf67[4];
        #pragma unroll
        for (int k = 0; k < 4; ++k) {
            const int row = rr + 32 * k;
            zf01[k] = (f32x2){zf_c[0][row], zf_c[1][row]};
            zf23[k] = (f32x2){zf_c[2][row], zf_c[3][row]};
            zf45[k] = (f32x2){zf_c[4][row], zf_c[5][row]};
            zf67[k] = (f32x2){zf_c[6][row], zf_c[7][row]};
        }
        f32x2 a01[4] = {}, a23[4] = {}, a45[4] = {}, a67[4] = {};
        #pragma unroll 4
        for (int i = 0; i < 64; ++i) {
            const int f = fs * 64 + i;
            const float4 wa = *reinterpret_cast<const float4*>(&w1_s[f][0]);
            const float4 wb = *reinterpret_cast<const float4*>(&w1_s[f][4]);
            const float bb = b1_s[f];
            const float4 ua = *reinterpret_cast<const float4*>(&w2t_s[f][0]);
            const float4 ub = *reinterpret_cast<const float4*>(&w2t_s[f][4]);
            const f32x2 wa01 = {wa.x, wa.y}, wa23 = {wa.z, wa.w};
            const f32x2 wb45 = {wb.x, wb.y}, wb67 = {wb.z, wb.w};
            const f32x2 ua01 = {ua.x, ua.y}, ua23 = {ua.z, ua.w};
            const f32x2 ub45 = {ub.x, ub.y}, ub67 = {ub.z, ub.w};
            #pragma unroll
            for (int k = 0; k < 4; ++k) {
                const f32x2 ha = zf01[k] * wa01 + zf23[k] * wa23;
                const f32x2 hb = zf45[k] * wb45 + zf67[k] * wb67;
                float hv = bb + ha.x + ha.y + hb.x + hb.y;
                hv = fmaxf(hv, 0.f);
                a01[k] += hv * ua01;  a23[k] += hv * ua23;
                a45[k] += hv * ub45;  a67[k] += hv * ub67;
            }
        }
        #pragma unroll
        for (int k = 0; k < 4; ++k) {
            const int row = rr + 32 * k;
            float* pf = &part_f[fs][row][0];
            pf[0] = a01[k].x; pf[1] = a01[k].y; pf[2] = a23[k].x; pf[3] = a23[k].y;
            pf[4] = a45[k].x; pf[5] = a45[k].y; pf[6] = a67[k].x; pf[7] = a67[k].y;
        }
    }
    __syncthreads();

    // ---- P6a: reduce f-splits, add residual + b2 ----
    {
        const int e = t >> 7, r = t & 127;
        float s = 0.f;
        #pragma unroll
        for (int fs = 0; fs < 8; ++fs) s += part_f[fs][r][e];
        zf_c[e][r] = x1_c[e][r] + s + b2_s[e];   // reuse zf_c as t2
    }
    __syncthreads();

    // ---- P6b: LN2 + store ----
    if (t < QPB) {
        float t2[NE];
        #pragma unroll
        for (int e = 0; e < NE; ++e) t2[e] = zf_c[e][t];
        float mu = 0.f;
        #pragma unroll
        for (int e = 0; e < NE; ++e) mu += t2[e];
        mu *= 0.125f;
        float var = 0.f;
        #pragma unroll
        for (int e = 0; e < NE; ++e) { const float d = t2[e] - mu; var += d * d; }
        var *= 0.125f;
        const float inv2 = rsqrtf(var + LNEPS);
        float o[NE];
        #pragma unroll
        for (int e = 0; e < NE; ++e) o[e] = (t2[e] - mu) * inv2 * g2_s[e] + be2_s[e];
        float4* o4 = reinterpret_cast<float4*>(out + ((size_t)b * NS + qc * QPB + t) * NE);
        o4[0] = make_float4(o[0], o[1], o[2], o[3]);
        o4[1] = make_float4(o[4], o[5], o[6], o[7]);
    }
}

extern "C" void kernel_launch(void* const* d_in, const int* in_sizes, int n_in,
                              void* d_out, int out_size, void* d_ws, size_t ws_size,
                              hipStream_t stream) {
    const float* x        = (const float*)d_in[0];
    const float* theta_rx = (const float*)d_in[1];
    const float* w_out    = (const float*)d_in[2];
    const float* theta_ry = (const float*)d_in[3];
    const float* w1       = (const float*)d_in[4];
    const float* b1       = (const float*)d_in[5];
    const float* w2       = (const float*)d_in[6];
    const float* b2       = (const float*)d_in[7];
    const float* g1       = (const float*)d_in[8];
    const float* be1      = (const float*)d_in[9];
    const float* g2       = (const float*)d_in[10];
    const float* be2      = (const float*)d_in[11];
    float* out = (float*)d_out;
    float* ws  = (float*)d_ws;

    k1_moments<<<dim3(NB * NH * NCHUNK), dim3(256), 0, stream>>>(x, theta_rx, ws);
    k2_main<<<dim3(NB * (NS / QPB)), dim3(1024), 0, stream>>>(
        x, theta_rx, w_out, theta_ry, w1, b1, w2, b2, g1, be1, g2, be2, ws, out);
}

// Round 14
// 33.025 us; speedup vs baseline: 1.8326x; 1.0861x over previous
//
#include <hip/hip_runtime.h>
#include <math.h>
#include <utility>

#define NB 16
#define NS 2048
#define NE 8
#define NH 2
#define NF 512
#define DEG 6
#define NMONO 210          // #monomials in 4 vars, total degree <= 6
#define KPB 64             // keys per k1 block
#define NCHUNK 32          // key chunks per (b,h)
#define PHI_LD 66          // fp16 row stride (64 keys + 2 pad)
#define QPB 128
#define LNEPS 1e-5f
#define PART_STRIDE (5 * NMONO)

typedef float f32x2 __attribute__((ext_vector_type(2)));
typedef _Float16 h2 __attribute__((ext_vector_type(2)));

#if defined(__has_builtin)
# if __has_builtin(__builtin_amdgcn_fdot2)
#  define FDOT2(a,b,c) __builtin_amdgcn_fdot2((a),(b),(c),false)
# endif
#endif
#ifndef FDOT2
static __device__ __forceinline__ float fdot2_sw(h2 a, h2 b, float c) {
    return c + (float)a.x * (float)b.x + (float)a.y * (float)b.y;
}
# define FDOT2(a,b,c) fdot2_sw((a),(b),(c))
#endif

// Degree-6 truncated Chebyshev approx of e^x on [-2,2] in t=x/2 (power basis).
constexpr float ACOEF_C[7] = {0.99994459f, 2.00308514f, 2.00174650f,
                              1.30890404f, 0.65803033f, 0.31441604f, 0.10241921f};

constexpr int mono_e(int idx) {
    int i = 0;
    for (int e0 = 0; e0 <= DEG; ++e0)
        for (int e1 = 0; e1 <= DEG - e0; ++e1)
            for (int e2 = 0; e2 <= DEG - e0 - e1; ++e2)
                for (int e3 = 0; e3 <= DEG - e0 - e1 - e2; ++e3) {
                    if (i == idx) return (e0 << 12) | (e1 << 8) | (e2 << 4) | e3;
                    ++i;
                }
    return 0;
}
constexpr float mfact(int n) { float r = 1.f; for (int i = 2; i <= n; ++i) r *= (float)i; return r; }
constexpr float mono_c(int idx) {
    const int E = mono_e(idx);
    const int e0 = E >> 12, e1 = (E >> 8) & 15, e2 = (E >> 4) & 15, e3 = E & 15;
    const int d = e0 + e1 + e2 + e3;
    return ACOEF_C[d] * (mfact(d) / (mfact(e0) * mfact(e1) * mfact(e2) * mfact(e3)));
}

template <int BEG, class F, int... Is>
__device__ __forceinline__ void sf_impl(F f, std::integer_sequence<int, Is...>) {
    (f(std::integral_constant<int, BEG + Is>{}), ...);
}
template <int BEG, int END, class F>
__device__ __forceinline__ void static_for(F f) {
    sf_impl<BEG>(f, std::make_integer_sequence<int, END - BEG>{});
}

// ---------------- K1: per-64-key-chunk partial moments (r6, known-good) ----
template <int BEG, int END>
__device__ __forceinline__ void phi_body(_Float16* __restrict__ Phi, int lane,
                                         const float (&pw0)[7], const float (&pw1)[7],
                                         const float (&pw2)[7], const float (&pw3)[7]) {
    static_for<BEG, END>([&](auto Ic) {
        constexpr int idx = Ic.value;
        constexpr int E = mono_e(idx);
        constexpr float C = mono_c(idx);
        const float v = C * (pw0[E >> 12] * pw1[(E >> 8) & 15]) *
                            (pw2[(E >> 4) & 15] * pw3[E & 15]);
        Phi[idx * PHI_LD + lane] = (_Float16)v;
    });
}

__global__ __launch_bounds__(256, 4)
void k1_moments(const float* __restrict__ x, const float* __restrict__ theta_rx,
                float* __restrict__ ws) {
    __shared__ _Float16 Phi[NMONO * PHI_LD];          // 27.7 KB
    __shared__ __align__(16) _Float16 kvh[KPB / 2][8];
    __shared__ float th_s[8];

    const int t = threadIdx.x, bid = blockIdx.x;
    const int kc = bid & 31, h = (bid >> 5) & 1, b = bid >> 6;

    if (t < 8) th_s[t] = theta_rx[t];
    __syncthreads();

    const int lane = t & 63, wq = t >> 6;
    {
        const float* xr = x + ((size_t)b * NS + kc * KPB + lane) * NE;
        const float4 v0 = *reinterpret_cast<const float4*>(xr);
        const float4 v1 = *reinterpret_cast<const float4*>(xr + 4);
        const float c0 = __cosf(v0.x + th_s[0]), c1 = __cosf(v0.y + th_s[1]);
        const float c2 = __cosf(v0.z + th_s[2]), c3 = __cosf(v0.w + th_s[3]);
        const float c4 = __cosf(v1.x + th_s[4]), c5 = __cosf(v1.y + th_s[5]);
        const float c6 = __cosf(v1.z + th_s[6]), c7 = __cosf(v1.w + th_s[7]);
        const float p1 = c0*c1, p2 = p1*c2, p3 = p2*c3, p4 = p3*c4;
        const float p5 = p4*c5, p6 = p5*c6, p7 = p6*c7;
        float k0, k1v, k2v, k3v;
        if (h == 0) {
            const float s6 = c7*c6, s5 = s6*c5, s4 = s5*c4, s3 = s4*c3, s2 = s3*c2;
            k0 = s2*c1; k1v = p1; k2v = p2; k3v = p3;
        } else {
            k0 = p4; k1v = p5; k2v = p6; k3v = p7;
        }
        if (t < 64) {
            const int j = t >> 1, par = t & 1;
            kvh[j][0 + par] = (_Float16)k0;  kvh[j][2 + par] = (_Float16)k1v;
            kvh[j][4 + par] = (_Float16)k2v; kvh[j][6 + par] = (_Float16)k3v;
        }
        float pw0[7], pw1[7], pw2[7], pw3[7];
        pw0[0] = pw1[0] = pw2[0] = pw3[0] = 1.f;
        #pragma unroll
        for (int i = 1; i <= DEG; ++i) {
            pw0[i] = pw0[i-1] * k0;  pw1[i] = pw1[i-1] * k1v;
            pw2[i] = pw2[i-1] * k2v; pw3[i] = pw3[i-1] * k3v;
        }
        switch (wq) {   // wave-uniform: each wave builds its quarter of Phi
            case 0: phi_body<0,   53 >(Phi, lane, pw0, pw1, pw2, pw3); break;
            case 1: phi_body<53,  106>(Phi, lane, pw0, pw1, pw2, pw3); break;
            case 2: phi_body<106, 159>(Phi, lane, pw0, pw1, pw2, pw3); break;
            default: phi_body<159, 210>(Phi, lane, pw0, pw1, pw2, pw3); break;
        }
    }
    __syncthreads();

    if (t < NMONO) {
        const h2 one2 = {(_Float16)1.f, (_Float16)1.f};
        float a0 = 0.f, a1 = 0.f, a2 = 0.f, a3 = 0.f, a4 = 0.f;
        #pragma unroll 8
        for (int j = 0; j < KPB / 2; ++j) {
            const h2 phi2 = *reinterpret_cast<const h2*>(&Phi[t * PHI_LD + 2 * j]);
            const float4 kv4 = *reinterpret_cast<const float4*>(&kvh[j][0]);
            const h2 kA = __builtin_bit_cast(h2, kv4.x);
            const h2 kB = __builtin_bit_cast(h2, kv4.y);
            const h2 kC = __builtin_bit_cast(h2, kv4.z);
            const h2 kD = __builtin_bit_cast(h2, kv4.w);
            a0 = FDOT2(phi2, kA, a0);
            a1 = FDOT2(phi2, kB, a1);
            a2 = FDOT2(phi2, kC, a2);
            a3 = FDOT2(phi2, kD, a3);
            a4 = FDOT2(phi2, one2, a4);
        }
        float* dst = ws + (size_t)bid * PART_STRIDE;
        dst[0 * NMONO + t] = a0;
        dst[1 * NMONO + t] = a1;
        dst[2 * NMONO + t] = a2;
        dst[3 * NMONO + t] = a3;
        dst[4 * NMONO + t] = a4;
    }
}

// ---------------- K2: no-spill P2 + full-wave P5 + XCD-local reduce --------
template <int BEG, int END>
__device__ __forceinline__ void p2_body1(const float4* __restrict__ Mn,
                                         const float* __restrict__ Md, int base,
                                         const float (&pw)[4][7],
                                         f32x2& a01, f32x2& a23, float& ad) {
    static_for<BEG, END>([&](auto Ic) {
        constexpr int idx = Ic.value;
        constexpr int E = mono_e(idx);
        constexpr int e0 = E >> 12, e1 = (E >> 8) & 15, e2 = (E >> 4) & 15, e3 = E & 15;
        const float4 mv = Mn[base + idx];     // wave-uniform broadcast
        const float  md = Md[base + idx];
        const float P = (pw[0][e0] * pw[1][e1]) * (pw[2][e2] * pw[3][e3]);
        a01 += P * (f32x2){mv.x, mv.y};
        a23 += P * (f32x2){mv.z, mv.w};
        ad  += P * md;
    });
}

__global__ __launch_bounds__(1024, 4)   // 4 waves/EU = 1 block/CU -> 128 VGPR cap
void k2_main(const float* __restrict__ x, const float* __restrict__ theta_rx,
             const float* __restrict__ w_out, const float* __restrict__ theta_ry,
             const float* __restrict__ w1, const float* __restrict__ b1,
             const float* __restrict__ w2, const float* __restrict__ b2,
             const float* __restrict__ g1, const float* __restrict__ be1,
             const float* __restrict__ g2, const float* __restrict__ be2,
             const float* __restrict__ ws, float* __restrict__ out) {
    __shared__ float4 Mn_lds[2 * NMONO];
    __shared__ float  Md_lds[2 * NMONO];
    __shared__ float  z_c[8][QPB];
    __shared__ float  x1_c[8][QPB];
    __shared__ float  zf_c[8][QPB];
    __shared__ float  attn_c[8][QPB];
    __shared__ float  part_a[4][256][5];
    __shared__ float  w1_s[NF][NE];
    __shared__ float  w2t_s[NF][NE];
    __shared__ float  b1_s[NF];
    __shared__ float  wout_s[NE][NE];
    __shared__ float  th_s[8], cry_s[8], g1_s[8], be1_s[8], g2_s[8], be2_s[8], b2_s[8];
    // ~80 KB

    const int t = threadIdx.x, bid = blockIdx.x;
    // XCD-aware remap (bijective): the 16 blocks of one batch share an XCD
    // (assuming XCD = bid % 8 round-robin) -> PART reduce hits L2 not L3.
    const int b  = (bid & 7) + 8 * ((bid >> 3) & 1);
    const int qc = bid >> 4;

    // ---- R1: reduce PART (32 chunks) -> moments in LDS ----
    if (t < 2 * NMONO) {
        const int h = (t >= NMONO) ? 1 : 0;
        const int a = t - h * NMONO;
        const float* src = ws + (size_t)((b * 2 + h) * NCHUNK) * PART_STRIDE;
        float s0 = 0.f, s1 = 0.f, s2 = 0.f, s3 = 0.f, s4 = 0.f;
        #pragma unroll 4
        for (int kc = 0; kc < NCHUNK; ++kc) {
            const float* p = src + (size_t)kc * PART_STRIDE;
            s0 += p[0 * NMONO + a]; s1 += p[1 * NMONO + a];
            s2 += p[2 * NMONO + a]; s3 += p[3 * NMONO + a];
            s4 += p[4 * NMONO + a];
        }
        Mn_lds[t] = make_float4(s0, s1, s2, s3);
        Md_lds[t] = s4;
    }

    // ---- stage weights ----
    for (int i = t; i < NF * NE; i += 1024) {
        ((float*)w1_s)[i] = w1[i];
        const int e = i >> 9, f = i & (NF - 1);
        w2t_s[f][e] = w2[i];
    }
    if (t < NF) b1_s[t] = b1[t];
    if (t < NE * NE) ((float*)wout_s)[t] = w_out[t];
    if (t < 8) {
        th_s[t]  = theta_rx[t];
        cry_s[t] = __cosf(theta_ry[t]);
        g1_s[t]  = g1[t];  be1_s[t] = be1[t];
        g2_s[t]  = g2[t];  be2_s[t] = be2[t];
        b2_s[t]  = b2[t];
    }
    __syncthreads();

    // ---- P1: z for the 128 query rows ----
    if (t < QPB) {
        const float* xr = x + ((size_t)b * NS + qc * QPB + t) * NE;
        const float4 v0 = *reinterpret_cast<const float4*>(xr);
        const float4 v1 = *reinterpret_cast<const float4*>(xr + 4);
        const float c0 = __cosf(v0.x + th_s[0]), c1 = __cosf(v0.y + th_s[1]);
        const float c2 = __cosf(v0.z + th_s[2]), c3 = __cosf(v0.w + th_s[3]);
        const float c4 = __cosf(v1.x + th_s[4]), c5 = __cosf(v1.y + th_s[5]);
        const float c6 = __cosf(v1.z + th_s[6]), c7 = __cosf(v1.w + th_s[7]);
        const float p1 = c0*c1, p2 = p1*c2, p3 = p2*c3, p4 = p3*c4;
        const float p5 = p4*c5, p6 = p5*c6, p7 = p6*c7;
        const float s6 = c7*c6, s5 = s6*c5, s4 = s5*c4, s3 = s4*c3, s2 = s3*c2;
        z_c[0][t] = s2*c1; z_c[1][t] = p1; z_c[2][t] = p2; z_c[3][t] = p3;
        z_c[4][t] = p4;    z_c[5][t] = p5; z_c[6][t] = p6; z_c[7][t] = p7;
    }
    __syncthreads();

    // ---- P2: 16 waves, wave = (g, h, r-half), ONE row per lane ----
    {
        const int w = t >> 6, lane = t & 63;
        const int g = w & 3;                 // monomial group (wave-uniform)
        const int h = (w >> 3) & 1;          // head (wave-uniform)
        const int r = ((w >> 2) & 1) * 64 + lane;
        float pw[4][7];
        #pragma unroll
        for (int d = 0; d < 4; ++d) {
            const float u = z_c[h*4+d][r] * 0.25f;
            pw[d][0] = 1.f;
            #pragma unroll
            for (int i = 1; i <= DEG; ++i) pw[d][i] = pw[d][i-1] * u;
        }
        f32x2 a01 = {0.f,0.f}, a23 = {0.f,0.f};
        float ad = 0.f;
        const int base = h * NMONO;
        switch (g) {   // wave-uniform branch
            case 0: p2_body1<0,   53 >(Mn_lds, Md_lds, base, pw, a01, a23, ad); break;
            case 1: p2_body1<53,  106>(Mn_lds, Md_lds, base, pw, a01, a23, ad); break;
            case 2: p2_body1<106, 159>(Mn_lds, Md_lds, base, pw, a01, a23, ad); break;
            default: p2_body1<159, 210>(Mn_lds, Md_lds, base, pw, a01, a23, ad); break;
        }
        float* pa = &part_a[g][h * 128 + r][0];
        pa[0] = a01.x; pa[1] = a01.y; pa[2] = a23.x; pa[3] = a23.y; pa[4] = ad;
    }
    __syncthreads();

    // ---- P3: combine groups, normalize ----
    if (t < 256) {
        const int h = t >> 7, r = t & 127;
        float n0 = 0.f, n1 = 0.f, n2 = 0.f, n3 = 0.f, dd = 0.f;
        #pragma unroll
        for (int g = 0; g < 4; ++g) {
            const float* pa = &part_a[g][t][0];
            n0 += pa[0]; n1 += pa[1]; n2 += pa[2]; n3 += pa[3]; dd += pa[4];
        }
        const float inv = 1.0f / dd;
        attn_c[h*4+0][r] = n0 * inv; attn_c[h*4+1][r] = n1 * inv;
        attn_c[h*4+2][r] = n2 * inv; attn_c[h*4+3][r] = n3 * inv;
    }
    __syncthreads();

    // ---- P4: out_proj -> LN1 -> zf (128 thr) ----
    if (t < QPB) {
        float av[NE];
        #pragma unroll
        for (int e = 0; e < NE; ++e) av[e] = attn_c[e][t];
        float y[NE];
        #pragma unroll
        for (int e = 0; e < NE; ++e) {
            float acc = 0.f;
            #pragma unroll
            for (int k = 0; k < NE; ++k) acc += av[k] * wout_s[e][k];
            y[e] = acc;
        }
        const float* xr = x + ((size_t)b * NS + qc * QPB + t) * NE;
        const float4 xv0 = *reinterpret_cast<const float4*>(xr);
        const float4 xv1 = *reinterpret_cast<const float4*>(xr + 4);
        float t1[NE];
        t1[0] = xv0.x + y[0]; t1[1] = xv0.y + y[1]; t1[2] = xv0.z + y[2]; t1[3] = xv0.w + y[3];
        t1[4] = xv1.x + y[4]; t1[5] = xv1.y + y[5]; t1[6] = xv1.z + y[6]; t1[7] = xv1.w + y[7];
        float mu = 0.f;
        #pragma unroll
        for (int e = 0; e < NE; ++e) mu += t1[e];
        mu *= 0.125f;
        float var = 0.f;
        #pragma unroll
        for (int e = 0; e < NE; ++e) { const float d = t1[e] - mu; var += d * d; }
        var *= 0.125f;
        const float inv1 = rsqrtf(var + LNEPS);
        #pragma unroll
        for (int e = 0; e < NE; ++e) {
            const float x1e = (t1[e] - mu) * inv1 * g1_s[e] + be1_s[e];
            x1_c[e][t] = x1e;
            zf_c[e][t] = cry_s[e] * __cosf(x1e);
        }
    }
    __syncthreads();

    // ---- P5: FFN with ALL 1024 threads (row = t>>3, f-split = t&7),
    //      shfl-butterfly reduce over the 8 adjacent sub-lanes,
    //      LN2 + store inline (no part_f, no extra barriers) ----
    {
        const int r = t >> 3, sub = t & 7;
        float zf[NE];
        #pragma unroll
        for (int e = 0; e < NE; ++e) zf[e] = zf_c[e][r];
        f32x2 a01 = {0.f,0.f}, a23 = {0.f,0.f}, a45 = {0.f,0.f}, a67 = {0.f,0.f};
        #pragma unroll 8
        for (int i = 0; i < 64; ++i) {
            const int f = sub + (i << 3);
            const float4 wa = *reinterpret_cast<const float4*>(&w1_s[f][0]);
            const float4 wb = *reinterpret_cast<const float4*>(&w1_s[f][4]);
            float hv = b1_s[f] + zf[0]*wa.x + zf[1]*wa.y + zf[2]*wa.z + zf[3]*wa.w
                               + zf[4]*wb.x + zf[5]*wb.y + zf[6]*wb.z + zf[7]*wb.w;
            hv = fmaxf(hv, 0.f);
            const float4 ua = *reinterpret_cast<const float4*>(&w2t_s[f][0]);
            const float4 ub = *reinterpret_cast<const float4*>(&w2t_s[f][4]);
            a01 += hv * (f32x2){ua.x, ua.y};
            a23 += hv * (f32x2){ua.z, ua.w};
            a45 += hv * (f32x2){ub.x, ub.y};
            a67 += hv * (f32x2){ub.z, ub.w};
        }
        float acc[NE] = {a01.x, a01.y, a23.x, a23.y, a45.x, a45.y, a67.x, a67.y};
        #pragma unroll
        for (int m = 1; m < 8; m <<= 1) {
            #pragma unroll
            for (int e = 0; e < NE; ++e) acc[e] += __shfl_xor(acc[e], m, 64);
        }
        float t2[NE];
        #pragma unroll
        for (int e = 0; e < NE; ++e) t2[e] = x1_c[e][r] + acc[e] + b2_s[e];
        float mu = 0.f;
        #pragma unroll
        for (int e = 0; e < NE; ++e) mu += t2[e];
        mu *= 0.125f;
        float var = 0.f;
        #pragma unroll
        for (int e = 0; e < NE; ++e) { const float d = t2[e] - mu; var += d * d; }
        var *= 0.125f;
        const float inv2 = rsqrtf(var + LNEPS);
        out[((size_t)b * NS + qc * QPB + r) * NE + sub] =
            (t2[sub] - mu) * inv2 * g2_s[sub] + be2_s[sub];
    }
}

extern "C" void kernel_launch(void* const* d_in, const int* in_sizes, int n_in,
                              void* d_out, int out_size, void* d_ws, size_t ws_size,
                              hipStream_t stream) {
    const float* x        = (const float*)d_in[0];
    const float* theta_rx = (const float*)d_in[1];
    const float* w_out    = (const float*)d_in[2];
    const float* theta_ry = (const float*)d_in[3];
    const float* w1       = (const float*)d_in[4];
    const float* b1       = (const float*)d_in[5];
    const float* w2       = (const float*)d_in[6];
    const float* b2       = (const float*)d_in[7];
    const float* g1       = (const float*)d_in[8];
    const float* be1      = (const float*)d_in[9];
    const float* g2       = (const float*)d_in[10];
    const float* be2      = (const float*)d_in[11];
    float* out = (float*)d_out;
    float* ws  = (float*)d_ws;

    k1_moments<<<dim3(NB * NH * NCHUNK), dim3(256), 0, stream>>>(x, theta_rx, ws);
    k2_main<<<dim3(NB * (NS / QPB)), dim3(1024), 0, stream>>>(
        x, theta_rx, w_out, theta_ry, w1, b1, w2, b2, g1, be1, g2, be2, ws, out);
}

// Round 15
// 29.536 us; speedup vs baseline: 2.0491x; 1.1181x over previous
//
#include <hip/hip_runtime.h>
#include <math.h>
#include <utility>

#define NB 16
#define NS 2048
#define NE 8
#define NH 2
#define NF 512
#define DEG 6
#define NMONO 210          // #monomials in 4 vars, total degree <= 6
#define KPB 64             // keys per k1 block
#define NCHUNK 32          // key chunks per (b,h)
#define PHI_LD 66          // fp16 row stride (64 keys + 2 pad)
#define QPB 128
#define LNEPS 1e-5f
#define PART_STRIDE (5 * NMONO)

typedef float f32x2 __attribute__((ext_vector_type(2)));
typedef _Float16 h2 __attribute__((ext_vector_type(2)));

#if defined(__has_builtin)
# if __has_builtin(__builtin_amdgcn_fdot2)
#  define FDOT2(a,b,c) __builtin_amdgcn_fdot2((a),(b),(c),false)
# endif
#endif
#ifndef FDOT2
static __device__ __forceinline__ float fdot2_sw(h2 a, h2 b, float c) {
    return c + (float)a.x * (float)b.x + (float)a.y * (float)b.y;
}
# define FDOT2(a,b,c) fdot2_sw((a),(b),(c))
#endif

// Degree-6 truncated Chebyshev approx of e^x on [-2,2] in t=x/2 (power basis).
constexpr float ACOEF_C[7] = {0.99994459f, 2.00308514f, 2.00174650f,
                              1.30890404f, 0.65803033f, 0.31441604f, 0.10241921f};

constexpr int mono_e(int idx) {
    int i = 0;
    for (int e0 = 0; e0 <= DEG; ++e0)
        for (int e1 = 0; e1 <= DEG - e0; ++e1)
            for (int e2 = 0; e2 <= DEG - e0 - e1; ++e2)
                for (int e3 = 0; e3 <= DEG - e0 - e1 - e2; ++e3) {
                    if (i == idx) return (e0 << 12) | (e1 << 8) | (e2 << 4) | e3;
                    ++i;
                }
    return 0;
}
constexpr float mfact(int n) { float r = 1.f; for (int i = 2; i <= n; ++i) r *= (float)i; return r; }
constexpr float mono_c(int idx) {
    const int E = mono_e(idx);
    const int e0 = E >> 12, e1 = (E >> 8) & 15, e2 = (E >> 4) & 15, e3 = E & 15;
    const int d = e0 + e1 + e2 + e3;
    return ACOEF_C[d] * (mfact(d) / (mfact(e0) * mfact(e1) * mfact(e2) * mfact(e3)));
}

template <int BEG, class F, int... Is>
__device__ __forceinline__ void sf_impl(F f, std::integer_sequence<int, Is...>) {
    (f(std::integral_constant<int, BEG + Is>{}), ...);
}
template <int BEG, int END, class F>
__device__ __forceinline__ void static_for(F f) {
    sf_impl<BEG>(f, std::make_integer_sequence<int, END - BEG>{});
}

// ---------------- K1: per-64-key-chunk partial moments (r6, known-good) ----
template <int BEG, int END>
__device__ __forceinline__ void phi_body(_Float16* __restrict__ Phi, int lane,
                                         const float (&pw0)[7], const float (&pw1)[7],
                                         const float (&pw2)[7], const float (&pw3)[7]) {
    static_for<BEG, END>([&](auto Ic) {
        constexpr int idx = Ic.value;
        constexpr int E = mono_e(idx);
        constexpr float C = mono_c(idx);
        const float v = C * (pw0[E >> 12] * pw1[(E >> 8) & 15]) *
                            (pw2[(E >> 4) & 15] * pw3[E & 15]);
        Phi[idx * PHI_LD + lane] = (_Float16)v;
    });
}

__global__ __launch_bounds__(256, 4)
void k1_moments(const float* __restrict__ x, const float* __restrict__ theta_rx,
                float* __restrict__ ws) {
    __shared__ _Float16 Phi[NMONO * PHI_LD];          // 27.7 KB
    __shared__ __align__(16) _Float16 kvh[KPB / 2][8];
    __shared__ float th_s[8];

    const int t = threadIdx.x, bid = blockIdx.x;
    const int kc = bid & 31, h = (bid >> 5) & 1, b = bid >> 6;

    if (t < 8) th_s[t] = theta_rx[t];
    __syncthreads();

    const int lane = t & 63, wq = t >> 6;
    {
        const float* xr = x + ((size_t)b * NS + kc * KPB + lane) * NE;
        const float4 v0 = *reinterpret_cast<const float4*>(xr);
        const float4 v1 = *reinterpret_cast<const float4*>(xr + 4);
        const float c0 = __cosf(v0.x + th_s[0]), c1 = __cosf(v0.y + th_s[1]);
        const float c2 = __cosf(v0.z + th_s[2]), c3 = __cosf(v0.w + th_s[3]);
        const float c4 = __cosf(v1.x + th_s[4]), c5 = __cosf(v1.y + th_s[5]);
        const float c6 = __cosf(v1.z + th_s[6]), c7 = __cosf(v1.w + th_s[7]);
        const float p1 = c0*c1, p2 = p1*c2, p3 = p2*c3, p4 = p3*c4;
        const float p5 = p4*c5, p6 = p5*c6, p7 = p6*c7;
        float k0, k1v, k2v, k3v;
        if (h == 0) {
            const float s6 = c7*c6, s5 = s6*c5, s4 = s5*c4, s3 = s4*c3, s2 = s3*c2;
            k0 = s2*c1; k1v = p1; k2v = p2; k3v = p3;
        } else {
            k0 = p4; k1v = p5; k2v = p6; k3v = p7;
        }
        if (t < 64) {
            const int j = t >> 1, par = t & 1;
            kvh[j][0 + par] = (_Float16)k0;  kvh[j][2 + par] = (_Float16)k1v;
            kvh[j][4 + par] = (_Float16)k2v; kvh[j][6 + par] = (_Float16)k3v;
        }
        float pw0[7], pw1[7], pw2[7], pw3[7];
        pw0[0] = pw1[0] = pw2[0] = pw3[0] = 1.f;
        #pragma unroll
        for (int i = 1; i <= DEG; ++i) {
            pw0[i] = pw0[i-1] * k0;  pw1[i] = pw1[i-1] * k1v;
            pw2[i] = pw2[i-1] * k2v; pw3[i] = pw3[i-1] * k3v;
        }
        switch (wq) {   // wave-uniform: each wave builds its quarter of Phi
            case 0: phi_body<0,   53 >(Phi, lane, pw0, pw1, pw2, pw3); break;
            case 1: phi_body<53,  106>(Phi, lane, pw0, pw1, pw2, pw3); break;
            case 2: phi_body<106, 159>(Phi, lane, pw0, pw1, pw2, pw3); break;
            default: phi_body<159, 210>(Phi, lane, pw0, pw1, pw2, pw3); break;
        }
    }
    __syncthreads();

    if (t < NMONO) {
        const h2 one2 = {(_Float16)1.f, (_Float16)1.f};
        float a0 = 0.f, a1 = 0.f, a2 = 0.f, a3 = 0.f, a4 = 0.f;
        #pragma unroll 8
        for (int j = 0; j < KPB / 2; ++j) {
            const h2 phi2 = *reinterpret_cast<const h2*>(&Phi[t * PHI_LD + 2 * j]);
            const float4 kv4 = *reinterpret_cast<const float4*>(&kvh[j][0]);
            const h2 kA = __builtin_bit_cast(h2, kv4.x);
            const h2 kB = __builtin_bit_cast(h2, kv4.y);
            const h2 kC = __builtin_bit_cast(h2, kv4.z);
            const h2 kD = __builtin_bit_cast(h2, kv4.w);
            a0 = FDOT2(phi2, kA, a0);
            a1 = FDOT2(phi2, kB, a1);
            a2 = FDOT2(phi2, kC, a2);
            a3 = FDOT2(phi2, kD, a3);
            a4 = FDOT2(phi2, one2, a4);
        }
        float* dst = ws + (size_t)bid * PART_STRIDE;
        dst[0 * NMONO + t] = a0;
        dst[1 * NMONO + t] = a1;
        dst[2 * NMONO + t] = a2;
        dst[3 * NMONO + t] = a3;
        dst[4 * NMONO + t] = a4;
    }
}

// ---------------- K2: no-spill P2 + fused P34 + fp16 full-wave P5 ----------
template <int BEG, int END>
__device__ __forceinline__ void p2_body1(const float4* __restrict__ Mn,
                                         const float* __restrict__ Md, int base,
                                         const float (&pw)[4][7],
                                         f32x2& a01, f32x2& a23, float& ad) {
    static_for<BEG, END>([&](auto Ic) {
        constexpr int idx = Ic.value;
        constexpr int E = mono_e(idx);
        constexpr int e0 = E >> 12, e1 = (E >> 8) & 15, e2 = (E >> 4) & 15, e3 = E & 15;
        const float4 mv = Mn[base + idx];     // wave-uniform broadcast
        const float  md = Md[base + idx];
        const float P = (pw[0][e0] * pw[1][e1]) * (pw[2][e2] * pw[3][e3]);
        a01 += P * (f32x2){mv.x, mv.y};
        a23 += P * (f32x2){mv.z, mv.w};
        ad  += P * md;
    });
}

__global__ __launch_bounds__(1024, 4)   // 1 block/CU -> 128 VGPR cap
void k2_main(const float* __restrict__ x, const float* __restrict__ theta_rx,
             const float* __restrict__ w_out, const float* __restrict__ theta_ry,
             const float* __restrict__ w1, const float* __restrict__ b1,
             const float* __restrict__ w2, const float* __restrict__ b2,
             const float* __restrict__ g1, const float* __restrict__ be1,
             const float* __restrict__ g2, const float* __restrict__ be2,
             const float* __restrict__ ws, float* __restrict__ out) {
    __shared__ float4 Mn_lds[2 * NMONO];
    __shared__ float  Md_lds[2 * NMONO];
    __shared__ float  z_c[8][QPB];
    __shared__ float  x1_c[8][QPB];
    __shared__ float  zf_c[8][QPB];
    __shared__ float  part_a[4][256][5];
    __shared__ __align__(16) _Float16 w1h[NF][8];   // 8 KB fp16
    __shared__ __align__(16) _Float16 w2th[NF][8];  // 8 KB fp16 (transposed w2)
    __shared__ float  b1_s[NF];
    __shared__ float  wout_s[NE][NE];
    __shared__ float  th_s[8], cry_s[8], g1_s[8], be1_s[8], g2_s[8], be2_s[8], b2_s[8];
    // ~59 KB

    const int t = threadIdx.x, bid = blockIdx.x;
    // XCD-aware remap (bijective): the 16 blocks of one batch share an XCD
    // (assuming XCD = bid % 8 round-robin) -> PART reduce hits L2 not L3.
    const int b  = (bid & 7) + 8 * ((bid >> 3) & 1);
    const int qc = bid >> 4;

    // ---- R1: reduce PART (32 chunks) -> moments in LDS ----
    if (t < 2 * NMONO) {
        const int h = (t >= NMONO) ? 1 : 0;
        const int a = t - h * NMONO;
        const float* src = ws + (size_t)((b * 2 + h) * NCHUNK) * PART_STRIDE;
        float s0 = 0.f, s1 = 0.f, s2 = 0.f, s3 = 0.f, s4 = 0.f;
        #pragma unroll 4
        for (int kc = 0; kc < NCHUNK; ++kc) {
            const float* p = src + (size_t)kc * PART_STRIDE;
            s0 += p[0 * NMONO + a]; s1 += p[1 * NMONO + a];
            s2 += p[2 * NMONO + a]; s3 += p[3 * NMONO + a];
            s4 += p[4 * NMONO + a];
        }
        Mn_lds[t] = make_float4(s0, s1, s2, s3);
        Md_lds[t] = s4;
    }

    // ---- stage weights (fp16 for the FFN) ----
    for (int i = t; i < NF * NE; i += 1024) {
        ((_Float16*)w1h)[i] = (_Float16)w1[i];
        const int e = i >> 9, f = i & (NF - 1);
        w2th[f][e] = (_Float16)w2[i];
    }
    if (t < NF) b1_s[t] = b1[t];
    if (t < NE * NE) ((float*)wout_s)[t] = w_out[t];
    if (t < 8) {
        th_s[t]  = theta_rx[t];
        cry_s[t] = __cosf(theta_ry[t]);
        g1_s[t]  = g1[t];  be1_s[t] = be1[t];
        g2_s[t]  = g2[t];  be2_s[t] = be2[t];
        b2_s[t]  = b2[t];
    }
    __syncthreads();

    // ---- P1: z for the 128 query rows ----
    if (t < QPB) {
        const float* xr = x + ((size_t)b * NS + qc * QPB + t) * NE;
        const float4 v0 = *reinterpret_cast<const float4*>(xr);
        const float4 v1 = *reinterpret_cast<const float4*>(xr + 4);
        const float c0 = __cosf(v0.x + th_s[0]), c1 = __cosf(v0.y + th_s[1]);
        const float c2 = __cosf(v0.z + th_s[2]), c3 = __cosf(v0.w + th_s[3]);
        const float c4 = __cosf(v1.x + th_s[4]), c5 = __cosf(v1.y + th_s[5]);
        const float c6 = __cosf(v1.z + th_s[6]), c7 = __cosf(v1.w + th_s[7]);
        const float p1 = c0*c1, p2 = p1*c2, p3 = p2*c3, p4 = p3*c4;
        const float p5 = p4*c5, p6 = p5*c6, p7 = p6*c7;
        const float s6 = c7*c6, s5 = s6*c5, s4 = s5*c4, s3 = s4*c3, s2 = s3*c2;
        z_c[0][t] = s2*c1; z_c[1][t] = p1; z_c[2][t] = p2; z_c[3][t] = p3;
        z_c[4][t] = p4;    z_c[5][t] = p5; z_c[6][t] = p6; z_c[7][t] = p7;
    }
    __syncthreads();

    // ---- P2: 16 waves, wave = (g, h, r-half), ONE row per lane ----
    {
        const int w = t >> 6, lane = t & 63;
        const int g = w & 3;                 // monomial group (wave-uniform)
        const int h = (w >> 3) & 1;          // head (wave-uniform)
        const int r = ((w >> 2) & 1) * 64 + lane;
        float pw[4][7];
        #pragma unroll
        for (int d = 0; d < 4; ++d) {
            const float u = z_c[h*4+d][r] * 0.25f;
            pw[d][0] = 1.f;
            #pragma unroll
            for (int i = 1; i <= DEG; ++i) pw[d][i] = pw[d][i-1] * u;
        }
        f32x2 a01 = {0.f,0.f}, a23 = {0.f,0.f};
        float ad = 0.f;
        const int base = h * NMONO;
        switch (g) {   // wave-uniform branch
            case 0: p2_body1<0,   53 >(Mn_lds, Md_lds, base, pw, a01, a23, ad); break;
            case 1: p2_body1<53,  106>(Mn_lds, Md_lds, base, pw, a01, a23, ad); break;
            case 2: p2_body1<106, 159>(Mn_lds, Md_lds, base, pw, a01, a23, ad); break;
            default: p2_body1<159, 210>(Mn_lds, Md_lds, base, pw, a01, a23, ad); break;
        }
        float* pa = &part_a[g][h * 128 + r][0];
        pa[0] = a01.x; pa[1] = a01.y; pa[2] = a23.x; pa[3] = a23.y; pa[4] = ad;
    }
    __syncthreads();

    // ---- P34 (fused P3+P4, ALL 1024 threads): combine -> attn -> out_proj
    //      -> LN1 (shfl over 8 sub-lanes) -> zf ----
    {
        const int r = t >> 3, sub = t & 7;
        float av[NE];
        #pragma unroll
        for (int h = 0; h < 2; ++h) {
            float n0 = 0.f, n1 = 0.f, n2 = 0.f, n3 = 0.f, dd = 0.f;
            #pragma unroll
            for (int g = 0; g < 4; ++g) {
                const float* pa = &part_a[g][h * 128 + r][0];   // broadcast reads
                n0 += pa[0]; n1 += pa[1]; n2 += pa[2]; n3 += pa[3]; dd += pa[4];
            }
            const float inv = 1.0f / dd;
            av[h*4+0] = n0 * inv; av[h*4+1] = n1 * inv;
            av[h*4+2] = n2 * inv; av[h*4+3] = n3 * inv;
        }
        float y = 0.f;
        #pragma unroll
        for (int k = 0; k < NE; ++k) y += av[k] * wout_s[sub][k];
        const float xv = x[((size_t)b * NS + qc * QPB + r) * NE + sub];  // coalesced
        const float t1 = xv + y;
        float mu = t1;
        mu += __shfl_xor(mu, 1, 64); mu += __shfl_xor(mu, 2, 64); mu += __shfl_xor(mu, 4, 64);
        mu *= 0.125f;
        const float d = t1 - mu;
        float var = d * d;
        var += __shfl_xor(var, 1, 64); var += __shfl_xor(var, 2, 64); var += __shfl_xor(var, 4, 64);
        var *= 0.125f;
        const float inv1 = rsqrtf(var + LNEPS);
        const float x1e = d * inv1 * g1_s[sub] + be1_s[sub];
        x1_c[sub][r] = x1e;
        zf_c[sub][r] = cry_s[sub] * __cosf(x1e);
    }
    __syncthreads();

    // ---- P5: fp16 FFN, ALL 1024 threads (row = t>>3, f-split = t&7),
    //      fdot2 h-dot, pk_fma_f16 out-acc, packed butterfly, LN2 + store ----
    {
        const int r = t >> 3, sub = t & 7;
        float zfl[NE];
        #pragma unroll
        for (int e = 0; e < NE; ++e) zfl[e] = zf_c[e][r];
        const h2 zp0 = {(_Float16)zfl[0], (_Float16)zfl[1]};
        const h2 zp1 = {(_Float16)zfl[2], (_Float16)zfl[3]};
        const h2 zp2 = {(_Float16)zfl[4], (_Float16)zfl[5]};
        const h2 zp3 = {(_Float16)zfl[6], (_Float16)zfl[7]};
        h2 acc0 = {(_Float16)0.f, (_Float16)0.f}, acc1 = acc0, acc2 = acc0, acc3 = acc0;
        #pragma unroll 8
        for (int i = 0; i < 64; ++i) {
            const int f = sub + (i << 3);
            const float4 wv = *reinterpret_cast<const float4*>(&w1h[f][0]);  // 8 fp16
            float hv = b1_s[f];
            hv = FDOT2(zp0, __builtin_bit_cast(h2, wv.x), hv);
            hv = FDOT2(zp1, __builtin_bit_cast(h2, wv.y), hv);
            hv = FDOT2(zp2, __builtin_bit_cast(h2, wv.z), hv);
            hv = FDOT2(zp3, __builtin_bit_cast(h2, wv.w), hv);
            hv = fmaxf(hv, 0.f);
            const _Float16 hh = (_Float16)hv;
            const h2 hv2 = {hh, hh};
            const float4 uv = *reinterpret_cast<const float4*>(&w2th[f][0]); // 8 fp16
            acc0 += hv2 * __builtin_bit_cast(h2, uv.x);   // v_pk_fma_f16
            acc1 += hv2 * __builtin_bit_cast(h2, uv.y);
            acc2 += hv2 * __builtin_bit_cast(h2, uv.z);
            acc3 += hv2 * __builtin_bit_cast(h2, uv.w);
        }
        // butterfly reduce over the 8 sub-lanes on packed fp16 pairs
        #pragma unroll
        for (int m = 1; m < 8; m <<= 1) {
            acc0 += __builtin_bit_cast(h2, __shfl_xor(__builtin_bit_cast(float, acc0), m, 64));
            acc1 += __builtin_bit_cast(h2, __shfl_xor(__builtin_bit_cast(float, acc1), m, 64));
            acc2 += __builtin_bit_cast(h2, __shfl_xor(__builtin_bit_cast(float, acc2), m, 64));
            acc3 += __builtin_bit_cast(h2, __shfl_xor(__builtin_bit_cast(float, acc3), m, 64));
        }
        float t2[NE];
        t2[0] = x1_c[0][r] + (float)acc0.x + b2_s[0];
        t2[1] = x1_c[1][r] + (float)acc0.y + b2_s[1];
        t2[2] = x1_c[2][r] + (float)acc1.x + b2_s[2];
        t2[3] = x1_c[3][r] + (float)acc1.y + b2_s[3];
        t2[4] = x1_c[4][r] + (float)acc2.x + b2_s[4];
        t2[5] = x1_c[5][r] + (float)acc2.y + b2_s[5];
        t2[6] = x1_c[6][r] + (float)acc3.x + b2_s[6];
        t2[7] = x1_c[7][r] + (float)acc3.y + b2_s[7];
        float mu = 0.f;
        #pragma unroll
        for (int e = 0; e < NE; ++e) mu += t2[e];
        mu *= 0.125f;
        float var = 0.f;
        #pragma unroll
        for (int e = 0; e < NE; ++e) { const float d = t2[e] - mu; var += d * d; }
        var *= 0.125f;
        const float inv2 = rsqrtf(var + LNEPS);
        out[((size_t)b * NS + qc * QPB + r) * NE + sub] =
            (t2[sub] - mu) * inv2 * g2_s[sub] + be2_s[sub];
    }
}

extern "C" void kernel_launch(void* const* d_in, const int* in_sizes, int n_in,
                              void* d_out, int out_size, void* d_ws, size_t ws_size,
                              hipStream_t stream) {
    const float* x        = (const float*)d_in[0];
    const float* theta_rx = (const float*)d_in[1];
    const float* w_out    = (const float*)d_in[2];
    const float* theta_ry = (const float*)d_in[3];
    const float* w1       = (const float*)d_in[4];
    const float* b1       = (const float*)d_in[5];
    const float* w2       = (const float*)d_in[6];
    const float* b2       = (const float*)d_in[7];
    const float* g1       = (const float*)d_in[8];
    const float* be1      = (const float*)d_in[9];
    const float* g2       = (const float*)d_in[10];
    const float* be2      = (const float*)d_in[11];
    float* out = (float*)d_out;
    float* ws  = (float*)d_ws;

    k1_moments<<<dim3(NB * NH * NCHUNK), dim3(256), 0, stream>>>(x, theta_rx, ws);
    k2_main<<<dim3(NB * (NS / QPB)), dim3(1024), 0, stream>>>(
        x, theta_rx, w_out, theta_ry, w1, b1, w2, b2, g1, be1, g2, be2, ws, out);
}

// Round 16
// 29.038 us; speedup vs baseline: 2.0842x; 1.0172x over previous
//
#include <hip/hip_runtime.h>
#include <math.h>
#include <utility>

#define NB 16
#define NS 2048
#define NE 8
#define NH 2
#define NF 512
#define DEG 6
#define NMONO 210          // #monomials in 4 vars, total degree <= 6
#define KPB 64             // keys per chunk-task
#define NCHUNK 32          // key chunks per (b,h)
#define PHI_LD 66          // fp16 row stride (64 keys + 2 pad)
#define QPB 128
#define LNEPS 1e-5f
#define PART_STRIDE (5 * NMONO)

typedef float f32x2 __attribute__((ext_vector_type(2)));
typedef _Float16 h2 __attribute__((ext_vector_type(2)));

#if defined(__has_builtin)
# if __has_builtin(__builtin_amdgcn_fdot2)
#  define FDOT2(a,b,c) __builtin_amdgcn_fdot2((a),(b),(c),false)
# endif
#endif
#ifndef FDOT2
static __device__ __forceinline__ float fdot2_sw(h2 a, h2 b, float c) {
    return c + (float)a.x * (float)b.x + (float)a.y * (float)b.y;
}
# define FDOT2(a,b,c) fdot2_sw((a),(b),(c))
#endif

// Degree-6 truncated Chebyshev approx of e^x on [-2,2] in t=x/2 (power basis).
constexpr float ACOEF_C[7] = {0.99994459f, 2.00308514f, 2.00174650f,
                              1.30890404f, 0.65803033f, 0.31441604f, 0.10241921f};

constexpr int mono_e(int idx) {
    int i = 0;
    for (int e0 = 0; e0 <= DEG; ++e0)
        for (int e1 = 0; e1 <= DEG - e0; ++e1)
            for (int e2 = 0; e2 <= DEG - e0 - e1; ++e2)
                for (int e3 = 0; e3 <= DEG - e0 - e1 - e2; ++e3) {
                    if (i == idx) return (e0 << 12) | (e1 << 8) | (e2 << 4) | e3;
                    ++i;
                }
    return 0;
}
constexpr float mfact(int n) { float r = 1.f; for (int i = 2; i <= n; ++i) r *= (float)i; return r; }
constexpr float mono_c(int idx) {
    const int E = mono_e(idx);
    const int e0 = E >> 12, e1 = (E >> 8) & 15, e2 = (E >> 4) & 15, e3 = E & 15;
    const int d = e0 + e1 + e2 + e3;
    return ACOEF_C[d] * (mfact(d) / (mfact(e0) * mfact(e1) * mfact(e2) * mfact(e3)));
}

template <int BEG, class F, int... Is>
__device__ __forceinline__ void sf_impl(F f, std::integer_sequence<int, Is...>) {
    (f(std::integral_constant<int, BEG + Is>{}), ...);
}
template <int BEG, int END, class F>
__device__ __forceinline__ void static_for(F f) {
    sf_impl<BEG>(f, std::make_integer_sequence<int, END - BEG>{});
}

// ---------------- K1: 2 chunk-tasks per 512-thread block ----------------
template <int BEG, int END>
__device__ __forceinline__ void phi_body(_Float16* __restrict__ Phi, int lane,
                                         const float (&pw0)[7], const float (&pw1)[7],
                                         const float (&pw2)[7], const float (&pw3)[7]) {
    static_for<BEG, END>([&](auto Ic) {
        constexpr int idx = Ic.value;
        constexpr int E = mono_e(idx);
        constexpr float C = mono_c(idx);
        const float v = C * (pw0[E >> 12] * pw1[(E >> 8) & 15]) *
                            (pw2[(E >> 4) & 15] * pw3[E & 15]);
        Phi[idx * PHI_LD + lane] = (_Float16)v;
    });
}

__global__ __launch_bounds__(512, 4)
void k1_moments(const float* __restrict__ x, const float* __restrict__ theta_rx,
                float* __restrict__ ws) {
    __shared__ _Float16 Phi[2][NMONO * PHI_LD];        // 2 x 27.7 KB
    __shared__ __align__(16) _Float16 kvh[2][KPB / 2][8];
    __shared__ float th_s[8];

    const int t = threadIdx.x, bid = blockIdx.x;
    const int g = t >> 8, tt = t & 255;
    const int tk = bid * 2 + g;                        // chunk-task id
    const int kc = tk & 31, h = (tk >> 5) & 1, b = tk >> 6;

    if (t < 8) th_s[t] = theta_rx[t];
    __syncthreads();

    const int lane = tt & 63, wq = tt >> 6;
    {
        const float* xr = x + ((size_t)b * NS + kc * KPB + lane) * NE;
        const float4 v0 = *reinterpret_cast<const float4*>(xr);
        const float4 v1 = *reinterpret_cast<const float4*>(xr + 4);
        const float c0 = __cosf(v0.x + th_s[0]), c1 = __cosf(v0.y + th_s[1]);
        const float c2 = __cosf(v0.z + th_s[2]), c3 = __cosf(v0.w + th_s[3]);
        const float c4 = __cosf(v1.x + th_s[4]), c5 = __cosf(v1.y + th_s[5]);
        const float c6 = __cosf(v1.z + th_s[6]), c7 = __cosf(v1.w + th_s[7]);
        const float p1 = c0*c1, p2 = p1*c2, p3 = p2*c3, p4 = p3*c4;
        const float p5 = p4*c5, p6 = p5*c6, p7 = p6*c7;
        float k0, k1v, k2v, k3v;
        if (h == 0) {
            const float s6 = c7*c6, s5 = s6*c5, s4 = s5*c4, s3 = s4*c3, s2 = s3*c2;
            k0 = s2*c1; k1v = p1; k2v = p2; k3v = p3;
        } else {
            k0 = p4; k1v = p5; k2v = p6; k3v = p7;
        }
        if (tt < 64) {
            const int j = tt >> 1, par = tt & 1;
            kvh[g][j][0 + par] = (_Float16)k0;  kvh[g][j][2 + par] = (_Float16)k1v;
            kvh[g][j][4 + par] = (_Float16)k2v; kvh[g][j][6 + par] = (_Float16)k3v;
        }
        float pw0[7], pw1[7], pw2[7], pw3[7];
        pw0[0] = pw1[0] = pw2[0] = pw3[0] = 1.f;
        #pragma unroll
        for (int i = 1; i <= DEG; ++i) {
            pw0[i] = pw0[i-1] * k0;  pw1[i] = pw1[i-1] * k1v;
            pw2[i] = pw2[i-1] * k2v; pw3[i] = pw3[i-1] * k3v;
        }
        _Float16* PhiG = &Phi[g][0];
        switch (wq) {   // wave-uniform: each wave builds its quarter of Phi
            case 0: phi_body<0,   53 >(PhiG, lane, pw0, pw1, pw2, pw3); break;
            case 1: phi_body<53,  106>(PhiG, lane, pw0, pw1, pw2, pw3); break;
            case 2: phi_body<106, 159>(PhiG, lane, pw0, pw1, pw2, pw3); break;
            default: phi_body<159, 210>(PhiG, lane, pw0, pw1, pw2, pw3); break;
        }
    }
    __syncthreads();

    if (tt < NMONO) {
        const h2 one2 = {(_Float16)1.f, (_Float16)1.f};
        const _Float16* PhiG = &Phi[g][0];
        float a0 = 0.f, a1 = 0.f, a2 = 0.f, a3 = 0.f, a4 = 0.f;
        #pragma unroll 8
        for (int j = 0; j < KPB / 2; ++j) {
            const h2 phi2 = *reinterpret_cast<const h2*>(&PhiG[tt * PHI_LD + 2 * j]);
            const float4 kv4 = *reinterpret_cast<const float4*>(&kvh[g][j][0]);
            const h2 kA = __builtin_bit_cast(h2, kv4.x);
            const h2 kB = __builtin_bit_cast(h2, kv4.y);
            const h2 kC = __builtin_bit_cast(h2, kv4.z);
            const h2 kD = __builtin_bit_cast(h2, kv4.w);
            a0 = FDOT2(phi2, kA, a0);
            a1 = FDOT2(phi2, kB, a1);
            a2 = FDOT2(phi2, kC, a2);
            a3 = FDOT2(phi2, kD, a3);
            a4 = FDOT2(phi2, one2, a4);
        }
        float* dst = ws + (size_t)tk * PART_STRIDE;
        dst[0 * NMONO + tt] = a0;
        dst[1 * NMONO + tt] = a1;
        dst[2 * NMONO + tt] = a2;
        dst[3 * NMONO + tt] = a3;
        dst[4 * NMONO + tt] = a4;
    }
}

// ---------------- K2: 3-barrier pipeline -----------------------------------
template <int BEG, int END>
__device__ __forceinline__ void p2_body1(const float4* __restrict__ Mn,
                                         const float* __restrict__ Md, int base,
                                         const float (&pw)[4][7],
                                         f32x2& a01, f32x2& a23, float& ad) {
    static_for<BEG, END>([&](auto Ic) {
        constexpr int idx = Ic.value;
        constexpr int E = mono_e(idx);
        constexpr int e0 = E >> 12, e1 = (E >> 8) & 15, e2 = (E >> 4) & 15, e3 = E & 15;
        const float4 mv = Mn[base + idx];     // wave-uniform broadcast
        const float  md = Md[base + idx];
        const float P = (pw[0][e0] * pw[1][e1]) * (pw[2][e2] * pw[3][e3]);
        a01 += P * (f32x2){mv.x, mv.y};
        a23 += P * (f32x2){mv.z, mv.w};
        ad  += P * md;
    });
}

__global__ __launch_bounds__(1024, 4)   // 1 block/CU -> 128 VGPR cap
void k2_main(const float* __restrict__ x, const float* __restrict__ theta_rx,
             const float* __restrict__ w_out, const float* __restrict__ theta_ry,
             const float* __restrict__ w1, const float* __restrict__ b1,
             const float* __restrict__ w2, const float* __restrict__ b2,
             const float* __restrict__ g1, const float* __restrict__ be1,
             const float* __restrict__ g2, const float* __restrict__ be2,
             const float* __restrict__ ws, float* __restrict__ out) {
    __shared__ float4 Mn_lds[2 * NMONO];
    __shared__ float  Md_lds[2 * NMONO];
    __shared__ float  z_c[8][QPB];
    __shared__ float  x1_c[8][QPB];
    __shared__ float  zf_c[8][QPB];
    __shared__ float  part_a[4][256][5];
    __shared__ __align__(16) _Float16 w1h[NF][8];   // 8 KB fp16
    __shared__ __align__(16) _Float16 w2th[NF][8];  // 8 KB fp16 (transposed w2)
    __shared__ float  b1_s[NF];
    __shared__ float  wout_s[NE][NE];
    __shared__ float  cry_s[8], g1_s[8], be1_s[8], g2_s[8], be2_s[8], b2_s[8];

    const int t = threadIdx.x, bid = blockIdx.x;
    // XCD-aware remap (bijective): the 16 blocks of one batch share an XCD.
    const int b  = (bid & 7) + 8 * ((bid >> 3) & 1);
    const int qc = bid >> 4;

    // ---- R1: reduce PART + stage weights + z rows, all concurrent ----
    if (t < 2 * NMONO) {
        const int h = (t >= NMONO) ? 1 : 0;
        const int a = t - h * NMONO;
        const float* src = ws + (size_t)((b * 2 + h) * NCHUNK) * PART_STRIDE;
        float s0 = 0.f, s1 = 0.f, s2 = 0.f, s3 = 0.f, s4 = 0.f;
        #pragma unroll 4
        for (int kc = 0; kc < NCHUNK; ++kc) {
            const float* p = src + (size_t)kc * PART_STRIDE;
            s0 += p[0 * NMONO + a]; s1 += p[1 * NMONO + a];
            s2 += p[2 * NMONO + a]; s3 += p[3 * NMONO + a];
            s4 += p[4 * NMONO + a];
        }
        Mn_lds[t] = make_float4(s0, s1, s2, s3);
        Md_lds[t] = s4;
    }
    for (int i = t; i < NF * NE; i += 1024) {
        ((_Float16*)w1h)[i] = (_Float16)w1[i];
        const int e = i >> 9, f = i & (NF - 1);
        w2th[f][e] = (_Float16)w2[i];
    }
    if (t < NF) b1_s[t] = b1[t];
    if (t < NE * NE) ((float*)wout_s)[t] = w_out[t];
    if (t < 8) {
        cry_s[t] = __cosf(theta_ry[t]);
        g1_s[t]  = g1[t];  be1_s[t] = be1[t];
        g2_s[t]  = g2[t];  be2_s[t] = be2[t];
        b2_s[t]  = b2[t];
    }
    if (t >= 896) {                     // z for the 128 query rows (theta from global)
        const int r = t - 896;
        const float* xr = x + ((size_t)b * NS + qc * QPB + r) * NE;
        const float4 v0 = *reinterpret_cast<const float4*>(xr);
        const float4 v1 = *reinterpret_cast<const float4*>(xr + 4);
        const float4 ta = *reinterpret_cast<const float4*>(theta_rx);
        const float4 tb = *reinterpret_cast<const float4*>(theta_rx + 4);
        const float c0 = __cosf(v0.x + ta.x), c1 = __cosf(v0.y + ta.y);
        const float c2 = __cosf(v0.z + ta.z), c3 = __cosf(v0.w + ta.w);
        const float c4 = __cosf(v1.x + tb.x), c5 = __cosf(v1.y + tb.y);
        const float c6 = __cosf(v1.z + tb.z), c7 = __cosf(v1.w + tb.w);
        const float p1 = c0*c1, p2 = p1*c2, p3 = p2*c3, p4 = p3*c4;
        const float p5 = p4*c5, p6 = p5*c6, p7 = p6*c7;
        const float s6 = c7*c6, s5 = s6*c5, s4 = s5*c4, s3 = s4*c3, s2 = s3*c2;
        z_c[0][r] = s2*c1; z_c[1][r] = p1; z_c[2][r] = p2; z_c[3][r] = p3;
        z_c[4][r] = p4;    z_c[5][r] = p5; z_c[6][r] = p6; z_c[7][r] = p7;
    }
    __syncthreads();

    // ---- P2: 16 waves, wave = (g, h, r-half), ONE row per lane ----
    {
        const int w = t >> 6, lane = t & 63;
        const int g = w & 3;                 // monomial group (wave-uniform)
        const int h = (w >> 3) & 1;          // head (wave-uniform)
        const int r = ((w >> 2) & 1) * 64 + lane;
        float pw[4][7];
        #pragma unroll
        for (int d = 0; d < 4; ++d) {
            const float u = z_c[h*4+d][r] * 0.25f;
            pw[d][0] = 1.f;
            #pragma unroll
            for (int i = 1; i <= DEG; ++i) pw[d][i] = pw[d][i-1] * u;
        }
        f32x2 a01 = {0.f,0.f}, a23 = {0.f,0.f};
        float ad = 0.f;
        const int base = h * NMONO;
        switch (g) {   // wave-uniform branch
            case 0: p2_body1<0,   53 >(Mn_lds, Md_lds, base, pw, a01, a23, ad); break;
            case 1: p2_body1<53,  106>(Mn_lds, Md_lds, base, pw, a01, a23, ad); break;
            case 2: p2_body1<106, 159>(Mn_lds, Md_lds, base, pw, a01, a23, ad); break;
            default: p2_body1<159, 210>(Mn_lds, Md_lds, base, pw, a01, a23, ad); break;
        }
        float* pa = &part_a[g][h * 128 + r][0];
        pa[0] = a01.x; pa[1] = a01.y; pa[2] = a23.x; pa[3] = a23.y; pa[4] = ad;
    }
    __syncthreads();

    // ---- P34 (ALL 1024 threads): combine -> attn -> out_proj -> LN1 -> zf ----
    {
        const int r = t >> 3, sub = t & 7;
        float av[NE];
        #pragma unroll
        for (int h = 0; h < 2; ++h) {
            float n0 = 0.f, n1 = 0.f, n2 = 0.f, n3 = 0.f, dd = 0.f;
            #pragma unroll
            for (int g = 0; g < 4; ++g) {
                const float* pa = &part_a[g][h * 128 + r][0];   // broadcast reads
                n0 += pa[0]; n1 += pa[1]; n2 += pa[2]; n3 += pa[3]; dd += pa[4];
            }
            const float inv = 1.0f / dd;
            av[h*4+0] = n0 * inv; av[h*4+1] = n1 * inv;
            av[h*4+2] = n2 * inv; av[h*4+3] = n3 * inv;
        }
        float y = 0.f;
        #pragma unroll
        for (int k = 0; k < NE; ++k) y += av[k] * wout_s[sub][k];
        const float xv = x[((size_t)b * NS + qc * QPB + r) * NE + sub];  // coalesced
        const float t1 = xv + y;
        float mu = t1;
        mu += __shfl_xor(mu, 1, 64); mu += __shfl_xor(mu, 2, 64); mu += __shfl_xor(mu, 4, 64);
        mu *= 0.125f;
        const float d = t1 - mu;
        float var = d * d;
        var += __shfl_xor(var, 1, 64); var += __shfl_xor(var, 2, 64); var += __shfl_xor(var, 4, 64);
        var *= 0.125f;
        const float inv1 = rsqrtf(var + LNEPS);
        const float x1e = d * inv1 * g1_s[sub] + be1_s[sub];
        x1_c[sub][r] = x1e;
        zf_c[sub][r] = cry_s[sub] * __cosf(x1e);
    }
    __syncthreads();

    // ---- P5: fp16 FFN, ALL 1024 threads, packed butterfly, LN2 + store ----
    {
        const int r = t >> 3, sub = t & 7;
        float zfl[NE];
        #pragma unroll
        for (int e = 0; e < NE; ++e) zfl[e] = zf_c[e][r];
        const h2 zp0 = {(_Float16)zfl[0], (_Float16)zfl[1]};
        const h2 zp1 = {(_Float16)zfl[2], (_Float16)zfl[3]};
        const h2 zp2 = {(_Float16)zfl[4], (_Float16)zfl[5]};
        const h2 zp3 = {(_Float16)zfl[6], (_Float16)zfl[7]};
        h2 acc0 = {(_Float16)0.f, (_Float16)0.f}, acc1 = acc0, acc2 = acc0, acc3 = acc0;
        #pragma unroll 8
        for (int i = 0; i < 64; ++i) {
            const int f = sub + (i << 3);
            const float4 wv = *reinterpret_cast<const float4*>(&w1h[f][0]);  // 8 fp16
            float hv = b1_s[f];
            hv = FDOT2(zp0, __builtin_bit_cast(h2, wv.x), hv);
            hv = FDOT2(zp1, __builtin_bit_cast(h2, wv.y), hv);
            hv = FDOT2(zp2, __builtin_bit_cast(h2, wv.z), hv);
            hv = FDOT2(zp3, __builtin_bit_cast(h2, wv.w), hv);
            hv = fmaxf(hv, 0.f);
            const _Float16 hh = (_Float16)hv;
            const h2 hv2 = {hh, hh};
            const float4 uv = *reinterpret_cast<const float4*>(&w2th[f][0]); // 8 fp16
            acc0 += hv2 * __builtin_bit_cast(h2, uv.x);   // v_pk_fma_f16
            acc1 += hv2 * __builtin_bit_cast(h2, uv.y);
            acc2 += hv2 * __builtin_bit_cast(h2, uv.z);
            acc3 += hv2 * __builtin_bit_cast(h2, uv.w);
        }
        #pragma unroll
        for (int m = 1; m < 8; m <<= 1) {
            acc0 += __builtin_bit_cast(h2, __shfl_xor(__builtin_bit_cast(float, acc0), m, 64));
            acc1 += __builtin_bit_cast(h2, __shfl_xor(__builtin_bit_cast(float, acc1), m, 64));
            acc2 += __builtin_bit_cast(h2, __shfl_xor(__builtin_bit_cast(float, acc2), m, 64));
            acc3 += __builtin_bit_cast(h2, __shfl_xor(__builtin_bit_cast(float, acc3), m, 64));
        }
        float t2[NE];
        t2[0] = x1_c[0][r] + (float)acc0.x + b2_s[0];
        t2[1] = x1_c[1][r] + (float)acc0.y + b2_s[1];
        t2[2] = x1_c[2][r] + (float)acc1.x + b2_s[2];
        t2[3] = x1_c[3][r] + (float)acc1.y + b2_s[3];
        t2[4] = x1_c[4][r] + (float)acc2.x + b2_s[4];
        t2[5] = x1_c[5][r] + (float)acc2.y + b2_s[5];
        t2[6] = x1_c[6][r] + (float)acc3.x + b2_s[6];
        t2[7] = x1_c[7][r] + (float)acc3.y + b2_s[7];
        float mu = 0.f;
        #pragma unroll
        for (int e = 0; e < NE; ++e) mu += t2[e];
        mu *= 0.125f;
        float var = 0.f;
        #pragma unroll
        for (int e = 0; e < NE; ++e) { const float d = t2[e] - mu; var += d * d; }
        var *= 0.125f;
        const float inv2 = rsqrtf(var + LNEPS);
        out[((size_t)b * NS + qc * QPB + r) * NE + sub] =
            (t2[sub] - mu) * inv2 * g2_s[sub] + be2_s[sub];
    }
}

extern "C" void kernel_launch(void* const* d_in, const int* in_sizes, int n_in,
                              void* d_out, int out_size, void* d_ws, size_t ws_size,
                              hipStream_t stream) {
    const float* x        = (const float*)d_in[0];
    const float* theta_rx = (const float*)d_in[1];
    const float* w_out    = (const float*)d_in[2];
    const float* theta_ry = (const float*)d_in[3];
    const float* w1       = (const float*)d_in[4];
    const float* b1       = (const float*)d_in[5];
    const float* w2       = (const float*)d_in[6];
    const float* b2       = (const float*)d_in[7];
    const float* g1       = (const float*)d_in[8];
    const float* be1      = (const float*)d_in[9];
    const float* g2       = (const float*)d_in[10];
    const float* be2      = (const float*)d_in[11];
    float* out = (float*)d_out;
    float* ws  = (float*)d_ws;

    k1_moments<<<dim3(NB * NH * NCHUNK / 2), dim3(512), 0, stream>>>(x, theta_rx, ws);
    k2_main<<<dim3(NB * (NS / QPB)), dim3(1024), 0, stream>>>(
        x, theta_rx, w_out, theta_ry, w1, b1, w2, b2, g1, be1, g2, be2, ws, out);
}